// Round 6
// baseline (1337.813 us; speedup 1.0000x reference)
//
#include <hip/hip_runtime.h>
#include <hip/hip_bf16.h>
#include <math.h>

#define N_NODES 100000
#define N_PAD   100096   // multiple of 256
#define N_EDGES 400000
#define IN_DIM  100
#define D       200
#define DP      208      // j padded to 13*16
#define KP      224      // k padded to 7*32
#define NUM_STEPS 4

#define TILE_CHUNKS 2688           // 6 gates * 7 kt * 64 lanes, 16B each = 43008 B
#define TILE_SHORTS (TILE_CHUNKS * 8)

typedef __attribute__((ext_vector_type(8))) short bfrag;   // 8 bf16 (4 VGPRs)
typedef __attribute__((ext_vector_type(4))) float facc;    // 4 fp32

// Wc[s] = w_ih @ W[s]^T so that gi = aggr_raw @ Wc[s]^T  (scatter is linear)
__device__ float g_Wc[NUM_STEPS * 600 * D];
// weights, per-(step,jt) CONTIGUOUS tile: [s][jt][g6][t7][lane64][8]
__device__ short g_Wall[NUM_STEPS * 13 * TILE_SHORTS];
__device__ float g_bias[6 * DP];

__device__ __forceinline__ float fast_sigmoid(float x) {
    return __builtin_amdgcn_rcpf(1.0f + __expf(-x));
}
__device__ __forceinline__ float fast_tanh(float x) {
    return 2.0f * __builtin_amdgcn_rcpf(1.0f + __expf(-2.0f * x)) - 1.0f;
}

// ---------------- Wc precompute: block=(s*600+j), thread=k ----------------
__global__ __launch_bounds__(256) void wc_kernel(const float* __restrict__ W,
                                                 const float* __restrict__ w_ih) {
    int s = blockIdx.x / 600;
    int j = blockIdx.x % 600;
    int k = threadIdx.x;
    if (k >= D) return;
    const float* wr = &w_ih[(size_t)j * D];
    const float* Wr = &W[(size_t)s * D * D + (size_t)k * D];
    float acc = 0.0f;
    #pragma unroll 4
    for (int t = 0; t < D; ++t) acc += wr[t] * Wr[t];
    g_Wc[((size_t)s * 600 + j) * D + k] = acc;
}

// ---------------- permute weights into per-tile fragment order (bf16) ----------------
// output idx = (((s*13 + jt)*6 + g)*7 + t)*64 + l, 8 shorts each
__global__ __launch_bounds__(256) void wconv_kernel(const float* __restrict__ w_hh) {
    int idx = blockIdx.x * 256 + threadIdx.x;   // < 4*13*6*7*64 = 139776
    int l  = idx & 63;
    int t  = (idx >> 6) % 7;
    int g  = (idx / 448) % 6;
    int jt = (idx / 2688) % 13;
    int s  = idx / 34944;
    int j  = jt * 16 + (l & 15);
    int k0 = t * 32 + (l >> 4) * 8;
    short* out = g_Wall + (size_t)idx * 8;
    #pragma unroll
    for (int i = 0; i < 8; ++i) {
        int k = k0 + i;
        float v = 0.0f;
        if (j < D && k < D)
            v = (g < 3) ? g_Wc[((size_t)s * 600 + g * 200 + j) * D + k]
                        : w_hh[((size_t)(g - 3) * 200 + j) * D + k];
        __hip_bfloat16 b = __float2bfloat16(v);
        out[i] = *reinterpret_cast<short*>(&b);
    }
}

__global__ void bias_kernel(const float* __restrict__ b_ih, const float* __restrict__ b_hh) {
    int idx = blockIdx.x * 256 + threadIdx.x;
    if (idx >= 6 * DP) return;
    int g = idx / DP, j = idx % DP;
    float v = 0.0f;
    if (j < D) v = (g < 3) ? b_ih[g * 200 + j] : b_hh[(g - 3) * 200 + j];
    g_bias[idx] = v;
}

// ---------------- pad: h[:, :100] = bf16(x), rest 0 ----------------
__global__ void pad_kernel(const float* __restrict__ x, __hip_bfloat16* __restrict__ h) {
    int idx = blockIdx.x * 256 + threadIdx.x;   // N_PAD*KP exact multiple of 256
    int n = idx / KP, c = idx % KP;
    float v = (n < N_NODES && c < IN_DIM) ? x[n * IN_DIM + c] : 0.0f;
    h[idx] = __float2bfloat16(v);
}

// ---------------- CSR build ----------------
__global__ void count_kernel(const int* __restrict__ dst, int* __restrict__ cnt) {
    int e = blockIdx.x * blockDim.x + threadIdx.x;
    if (e < N_EDGES) atomicAdd(&cnt[dst[e]], 1);
}

#define SCAN_B 1024
__global__ __launch_bounds__(SCAN_B) void scan1(const int* __restrict__ cnt,
                                                int* __restrict__ incl, int* __restrict__ bsum) {
    __shared__ int sh[SCAN_B];
    int i = blockIdx.x * SCAN_B + threadIdx.x;
    int v = (i < N_NODES) ? cnt[i] : 0;
    sh[threadIdx.x] = v; __syncthreads();
    for (int off = 1; off < SCAN_B; off <<= 1) {
        int t = (threadIdx.x >= off) ? sh[threadIdx.x - off] : 0;
        __syncthreads();
        sh[threadIdx.x] += t;
        __syncthreads();
    }
    if (i < N_NODES) incl[i] = sh[threadIdx.x];
    if (threadIdx.x == SCAN_B - 1) bsum[blockIdx.x] = sh[threadIdx.x];
}
__global__ void scan2(int* __restrict__ bsum, int nb) {
    __shared__ int sh[128];
    int v = (threadIdx.x < nb) ? bsum[threadIdx.x] : 0;
    sh[threadIdx.x] = v; __syncthreads();
    for (int off = 1; off < 128; off <<= 1) {
        int t = (threadIdx.x >= off) ? sh[threadIdx.x - off] : 0;
        __syncthreads();
        sh[threadIdx.x] += t;
        __syncthreads();
    }
    if (threadIdx.x < nb) bsum[threadIdx.x] = sh[threadIdx.x] - v;  // exclusive
}
__global__ void scan3(const int* __restrict__ cnt, const int* __restrict__ incl,
                      const int* __restrict__ bsum, int* __restrict__ off,
                      int* __restrict__ cursor) {
    int i = blockIdx.x * blockDim.x + threadIdx.x;
    if (i < N_NODES) {
        int v = incl[i] - cnt[i] + bsum[i / SCAN_B];
        off[i] = v; cursor[i] = v;
    }
    if (i == 0) off[N_NODES] = N_EDGES;
}
__global__ void fill_kernel(const int* __restrict__ src, const int* __restrict__ dst,
                            int* __restrict__ cursor, int* __restrict__ esrc) {
    int e = blockIdx.x * blockDim.x + threadIdx.x;
    if (e < N_EDGES) {
        int pos = atomicAdd(&cursor[dst[e]], 1);
        esrc[pos] = src[e];
    }
}

// ---------------- gather: aggr[n] = sum over in-edges of h[src] ----------------
// wave per node; lane < 56 handles 4 cols (8B ushort4); cols >= 200 forced zero
__global__ __launch_bounds__(256) void gather_kernel(const __hip_bfloat16* __restrict__ h,
                                                     const int* __restrict__ off,
                                                     const int* __restrict__ esrc,
                                                     __hip_bfloat16* __restrict__ aggr) {
    int wave = threadIdx.x >> 6, lane = threadIdx.x & 63;
    int n = blockIdx.x * 4 + wave;
    if (n >= N_PAD) return;
    int col = lane * 4;
    bool store_l = (lane < 56);
    bool sum_l   = (col < D);     // lanes 0..49
    float a0 = 0, a1 = 0, a2 = 0, a3 = 0;
    if (n < N_NODES && sum_l) {
        int e0 = off[n], e1 = off[n + 1];
        int e = e0;
        for (; e + 3 < e1; e += 4) {
            const ushort4 v0 = *(const ushort4*)(h + (size_t)esrc[e] * KP + col);
            const ushort4 v1 = *(const ushort4*)(h + (size_t)esrc[e + 1] * KP + col);
            const ushort4 v2 = *(const ushort4*)(h + (size_t)esrc[e + 2] * KP + col);
            const ushort4 v3 = *(const ushort4*)(h + (size_t)esrc[e + 3] * KP + col);
            a0 += __bfloat162float(*(const __hip_bfloat16*)&v0.x) + __bfloat162float(*(const __hip_bfloat16*)&v1.x)
                + __bfloat162float(*(const __hip_bfloat16*)&v2.x) + __bfloat162float(*(const __hip_bfloat16*)&v3.x);
            a1 += __bfloat162float(*(const __hip_bfloat16*)&v0.y) + __bfloat162float(*(const __hip_bfloat16*)&v1.y)
                + __bfloat162float(*(const __hip_bfloat16*)&v2.y) + __bfloat162float(*(const __hip_bfloat16*)&v3.y);
            a2 += __bfloat162float(*(const __hip_bfloat16*)&v0.z) + __bfloat162float(*(const __hip_bfloat16*)&v1.z)
                + __bfloat162float(*(const __hip_bfloat16*)&v2.z) + __bfloat162float(*(const __hip_bfloat16*)&v3.z);
            a3 += __bfloat162float(*(const __hip_bfloat16*)&v0.w) + __bfloat162float(*(const __hip_bfloat16*)&v1.w)
                + __bfloat162float(*(const __hip_bfloat16*)&v2.w) + __bfloat162float(*(const __hip_bfloat16*)&v3.w);
        }
        for (; e < e1; ++e) {
            const ushort4 v = *(const ushort4*)(h + (size_t)esrc[e] * KP + col);
            a0 += __bfloat162float(*(const __hip_bfloat16*)&v.x);
            a1 += __bfloat162float(*(const __hip_bfloat16*)&v.y);
            a2 += __bfloat162float(*(const __hip_bfloat16*)&v.z);
            a3 += __bfloat162float(*(const __hip_bfloat16*)&v.w);
        }
    }
    if (store_l) {
        __hip_bfloat16 o[4];
        o[0] = __float2bfloat16(a0); o[1] = __float2bfloat16(a1);
        o[2] = __float2bfloat16(a2); o[3] = __float2bfloat16(a3);
        *(ushort4*)(aggr + (size_t)n * KP + col) = *(const ushort4*)o;
    }
}

// ---------------- async stage: one jt tile (43008 B) global -> LDS ----------------
__device__ __forceinline__ void stage_tile(const short* __restrict__ gsrc,
                                           short* lds_dst, int wave, int lane) {
    // 42 wave-groups of 64 chunks x 16B; wave-uniform LDS base + lane*16
    for (int g = wave; g < 42; g += 4) {
        __builtin_amdgcn_global_load_lds(
            (const __attribute__((address_space(1))) void*)(gsrc + g * 512 + lane * 8),
            (__attribute__((address_space(3))) void*)(lds_dst + g * 512),
            16, 0, 0);
    }
}

// ---------------- MFMA GRU: A/H in registers, B double-buffered via async LDS ----------------
// grid N_PAD/128; block 256 = 4 waves; wave: 32 rows, sweeps 13 j-tiles x 6 gates
__global__ __launch_bounds__(256, 1) void gru_mfma(const __hip_bfloat16* __restrict__ aggr,
                                                   const __hip_bfloat16* __restrict__ hcur,
                                                   __hip_bfloat16* __restrict__ hnext,
                                                   int step) {
    __shared__ short Bs[2][TILE_SHORTS];   // 2 x 43008 B
    int tid = threadIdx.x;
    int lane = tid & 63, wave = tid >> 6;
    int mw = blockIdx.x * 128 + wave * 32;
    int mrow = lane & 15, kq = lane >> 4;
    size_t abase = (size_t)(mw + mrow) * KP + kq * 8;

    const short* Wstep = g_Wall + (size_t)step * 13 * TILE_SHORTS;

    // prefetch jt=0 tile into buffer 0 (DMA, no VGPR round-trip)
    stage_tile(Wstep, &Bs[0][0], wave, lane);

    // load this wave's A/H fragments once (32 rows x 224 cols each)
    bfrag av[2][7], hv[2][7];
    #pragma unroll
    for (int mf = 0; mf < 2; ++mf)
        #pragma unroll
        for (int t = 0; t < 7; ++t) {
            av[mf][t] = *(const bfrag*)(aggr + abase + mf * 16 * KP + t * 32);
            hv[mf][t] = *(const bfrag*)(hcur + abase + mf * 16 * KP + t * 32);
        }

    int jcol = lane & 15;
    int rowq = (lane >> 4) * 4;

    __syncthreads();   // drains vmcnt: buffer 0 staged, A/H in regs

    for (int jt = 0; jt < 13; ++jt) {
        // issue prefetch of next tile into the other buffer (overlaps compute below)
        if (jt + 1 < 13)
            stage_tile(Wstep + (size_t)(jt + 1) * TILE_SHORTS, &Bs[(jt + 1) & 1][0], wave, lane);

        int j = jt * 16 + jcol;
        // preload old-h values (latency hides under compute)
        __hip_bfloat16 hold_b[2][4];
        #pragma unroll
        for (int mf = 0; mf < 2; ++mf)
            #pragma unroll
            for (int r = 0; r < 4; ++r)
                hold_b[mf][r] = hcur[(size_t)(mw + mf * 16 + rowq + r) * KP + j];

        const short* Bcur = &Bs[jt & 1][0];
        facc acc[6][2];
        #pragma unroll
        for (int g = 0; g < 6; ++g)
            #pragma unroll
            for (int mf = 0; mf < 2; ++mf) acc[g][mf] = (facc)(0.0f);

        #pragma unroll
        for (int t = 0; t < 7; ++t) {
            bfrag bv[6];
            #pragma unroll
            for (int g = 0; g < 6; ++g)
                bv[g] = *(const bfrag*)&Bcur[(size_t)(((g * 7 + t) * 64) + lane) * 8];
            #pragma unroll
            for (int g = 0; g < 3; ++g)
                #pragma unroll
                for (int mf = 0; mf < 2; ++mf) {
                    acc[g][mf]     = __builtin_amdgcn_mfma_f32_16x16x32_bf16(av[mf][t], bv[g],     acc[g][mf],     0, 0, 0);
                    acc[g + 3][mf] = __builtin_amdgcn_mfma_f32_16x16x32_bf16(hv[mf][t], bv[g + 3], acc[g + 3][mf], 0, 0, 0);
                }
        }

        // epilogue: C/D layout col=lane&15 (j), row=(lane>>4)*4+reg (m)
        if (j < D) {
            float bir = g_bias[j],          biz = g_bias[DP + j],     bin = g_bias[2 * DP + j];
            float bhr = g_bias[3 * DP + j], bhz = g_bias[4 * DP + j], bhn = g_bias[5 * DP + j];
            #pragma unroll
            for (int mf = 0; mf < 2; ++mf) {
                int m0 = mw + mf * 16 + rowq;
                #pragma unroll
                for (int r = 0; r < 4; ++r) {
                    int m = m0 + r;
                    if (m < N_NODES) {
                        float hold = __bfloat162float(hold_b[mf][r]);
                        float rr = fast_sigmoid(acc[0][mf][r] + bir + acc[3][mf][r] + bhr);
                        float zz = fast_sigmoid(acc[1][mf][r] + biz + acc[4][mf][r] + bhz);
                        float nn = fast_tanh(acc[2][mf][r] + bin + rr * (acc[5][mf][r] + bhn));
                        hnext[(size_t)m * KP + j] = __float2bfloat16((1.0f - zz) * nn + zz * hold);
                    }
                }
            }
        }
        __syncthreads();   // waits vmcnt(0): next tile staged; also fences Bs reads
    }
}

// ---------------- relu + column-max (bits trick, relu >= 0) ----------------
#define POOL_CHUNK 512
__global__ void pool_kernel(const __hip_bfloat16* __restrict__ h, unsigned int* __restrict__ pooled) {
    int d = threadIdx.x;
    if (d >= D) return;
    int n0 = blockIdx.x * POOL_CHUNK;
    float mx = 0.0f;
    for (int i = 0; i < POOL_CHUNK; ++i) {
        int n = n0 + i;
        if (n >= N_NODES) break;
        float v = __bfloat162float(h[(size_t)n * KP + d]);
        v = v > 0.0f ? v : 0.0f;
        mx = v > mx ? v : mx;
    }
    atomicMax(&pooled[d], __float_as_uint(mx));
}

// ---------------- logits + softmax ----------------
__global__ void head_kernel(const unsigned int* __restrict__ pooled,
                            const float* __restrict__ cls_w,
                            const float* __restrict__ cls_b,
                            float* __restrict__ out) {
    if (threadIdx.x == 0) {
        float l0 = cls_b[0], l1 = cls_b[1];
        for (int d = 0; d < D; ++d) {
            float p = __uint_as_float(pooled[d]);
            l0 += p * cls_w[d];
            l1 += p * cls_w[D + d];
        }
        float mx = l0 > l1 ? l0 : l1;
        float e0 = expf(l0 - mx), e1 = expf(l1 - mx);
        out[0] = e0 / (e0 + e1);
        out[1] = e1 / (e0 + e1);
    }
}

extern "C" void kernel_launch(void* const* d_in, const int* in_sizes, int n_in,
                              void* d_out, int out_size, void* d_ws, size_t ws_size,
                              hipStream_t stream) {
    const float* x     = (const float*)d_in[0];
    const float* W     = (const float*)d_in[1];
    const float* w_ih  = (const float*)d_in[2];
    const float* w_hh  = (const float*)d_in[3];
    const float* b_ih  = (const float*)d_in[4];
    const float* b_hh  = (const float*)d_in[5];
    const float* cls_w = (const float*)d_in[6];
    const float* cls_b = (const float*)d_in[7];
    const int*   ei    = (const int*)d_in[8];
    const int* src = ei;
    const int* dst = ei + N_EDGES;

    const size_t ROWB = (size_t)N_PAD * KP;     // bf16 elements per buffer
    __hip_bfloat16* hA   = (__hip_bfloat16*)d_ws;
    __hip_bfloat16* hB   = hA + ROWB;
    __hip_bfloat16* aggr = hB + ROWB;
    int* cnt    = (int*)(aggr + ROWB);
    int* incl   = cnt + N_NODES;
    int* bsum   = incl + N_NODES;
    int* off    = bsum + 128;
    int* cursor = off + N_NODES + 1;
    int* esrc   = cursor + N_NODES;
    unsigned int* pooled = (unsigned int*)(esrc + N_EDGES);

    // CSR build (once per call; edges are step-invariant)
    hipMemsetAsync(cnt, 0, N_NODES * sizeof(int), stream);
    count_kernel<<<(N_EDGES + 255) / 256, 256, 0, stream>>>(dst, cnt);
    scan1<<<(N_NODES + SCAN_B - 1) / SCAN_B, SCAN_B, 0, stream>>>(cnt, incl, bsum);
    scan2<<<1, 128, 0, stream>>>(bsum, (N_NODES + SCAN_B - 1) / SCAN_B);
    scan3<<<(N_NODES + 255) / 256, 256, 0, stream>>>(cnt, incl, bsum, off, cursor);
    fill_kernel<<<(N_EDGES + 255) / 256, 256, 0, stream>>>(src, dst, cursor, esrc);

    // weight prep
    wc_kernel<<<NUM_STEPS * 600, 256, 0, stream>>>(W, w_ih);
    wconv_kernel<<<(NUM_STEPS * 13 * 6 * 7 * 64) / 256, 256, 0, stream>>>(w_hh);
    bias_kernel<<<(6 * DP + 255) / 256, 256, 0, stream>>>(b_ih, b_hh);

    pad_kernel<<<(int)(ROWB / 256), 256, 0, stream>>>(x, hA);

    __hip_bfloat16* hcur = hA;
    __hip_bfloat16* hnext = hB;
    for (int s = 0; s < NUM_STEPS; ++s) {
        gather_kernel<<<N_PAD / 4, 256, 0, stream>>>(hcur, off, esrc, aggr);
        gru_mfma<<<N_PAD / 128, 256, 0, stream>>>(aggr, hcur, hnext, s);
        __hip_bfloat16* t = hcur; hcur = hnext; hnext = t;
    }
    hipMemsetAsync(pooled, 0, D * sizeof(unsigned int), stream);
    pool_kernel<<<(N_NODES + POOL_CHUNK - 1) / POOL_CHUNK, 256, 0, stream>>>(hcur, pooled);
    head_kernel<<<1, 64, 0, stream>>>(pooled, cls_w, cls_b, (float*)d_out);
}

// Round 7
// 1268.667 us; speedup vs baseline: 1.0545x; 1.0545x over previous
//
#include <hip/hip_runtime.h>
#include <hip/hip_bf16.h>
#include <math.h>

#define N_NODES 100000
#define N_PAD   100096   // multiple of 256
#define N_EDGES 400000
#define IN_DIM  100
#define D       200
#define DP      208      // j padded to 13*16
#define KP      224      // k padded to 7*32
#define NUM_STEPS 4

#define TILE_CHUNKS 2688           // 6 gates * 7 kt * 64 lanes, 16B each = 43008 B
#define TILE_SHORTS (TILE_CHUNKS * 8)

typedef __attribute__((ext_vector_type(8))) short bfrag;   // 8 bf16 (4 VGPRs)
typedef __attribute__((ext_vector_type(4))) float facc;    // 4 fp32

// Wc[s] = w_ih @ W[s]^T so that gi = aggr_raw @ Wc[s]^T  (scatter is linear)
__device__ float g_Wc[NUM_STEPS * 600 * D];
// weights, per-(step,jt) CONTIGUOUS tile: [s][jt][g6][t7][lane64][8]
__device__ short g_Wall[NUM_STEPS * 13 * TILE_SHORTS];
__device__ float g_bias[6 * DP];

__device__ __forceinline__ float fast_sigmoid(float x) {
    return __builtin_amdgcn_rcpf(1.0f + __expf(-x));
}
__device__ __forceinline__ float fast_tanh(float x) {
    return 2.0f * __builtin_amdgcn_rcpf(1.0f + __expf(-2.0f * x)) - 1.0f;
}

// ---------------- Wc precompute: block=(s*600+j), thread=k ----------------
__global__ __launch_bounds__(256) void wc_kernel(const float* __restrict__ W,
                                                 const float* __restrict__ w_ih) {
    int s = blockIdx.x / 600;
    int j = blockIdx.x % 600;
    int k = threadIdx.x;
    if (k >= D) return;
    const float* wr = &w_ih[(size_t)j * D];
    const float* Wr = &W[(size_t)s * D * D + (size_t)k * D];
    float acc = 0.0f;
    #pragma unroll 4
    for (int t = 0; t < D; ++t) acc += wr[t] * Wr[t];
    g_Wc[((size_t)s * 600 + j) * D + k] = acc;
}

// ---------------- permute weights into per-tile fragment order (bf16) ----------------
// output idx = (((s*13 + jt)*6 + g)*7 + t)*64 + l, 8 shorts each
__global__ __launch_bounds__(256) void wconv_kernel(const float* __restrict__ w_hh) {
    int idx = blockIdx.x * 256 + threadIdx.x;   // < 4*13*6*7*64 = 139776
    int l  = idx & 63;
    int t  = (idx >> 6) % 7;
    int g  = (idx / 448) % 6;
    int jt = (idx / 2688) % 13;
    int s  = idx / 34944;
    int j  = jt * 16 + (l & 15);
    int k0 = t * 32 + (l >> 4) * 8;
    short* out = g_Wall + (size_t)idx * 8;
    #pragma unroll
    for (int i = 0; i < 8; ++i) {
        int k = k0 + i;
        float v = 0.0f;
        if (j < D && k < D)
            v = (g < 3) ? g_Wc[((size_t)s * 600 + g * 200 + j) * D + k]
                        : w_hh[((size_t)(g - 3) * 200 + j) * D + k];
        __hip_bfloat16 b = __float2bfloat16(v);
        out[i] = *reinterpret_cast<short*>(&b);
    }
}

__global__ void bias_kernel(const float* __restrict__ b_ih, const float* __restrict__ b_hh) {
    int idx = blockIdx.x * 256 + threadIdx.x;
    if (idx >= 6 * DP) return;
    int g = idx / DP, j = idx % DP;
    float v = 0.0f;
    if (j < D) v = (g < 3) ? b_ih[g * 200 + j] : b_hh[(g - 3) * 200 + j];
    g_bias[idx] = v;
}

// ---------------- pad: h[:, :100] = bf16(x), rest 0 ----------------
__global__ void pad_kernel(const float* __restrict__ x, __hip_bfloat16* __restrict__ h) {
    int idx = blockIdx.x * 256 + threadIdx.x;   // N_PAD*KP exact multiple of 256
    int n = idx / KP, c = idx % KP;
    float v = (n < N_NODES && c < IN_DIM) ? x[n * IN_DIM + c] : 0.0f;
    h[idx] = __float2bfloat16(v);
}

// ---------------- CSR build ----------------
__global__ void count_kernel(const int* __restrict__ dst, int* __restrict__ cnt) {
    int e = blockIdx.x * blockDim.x + threadIdx.x;
    if (e < N_EDGES) atomicAdd(&cnt[dst[e]], 1);
}

#define SCAN_B 1024
// 2-barrier block scan: wave shuffle-scan + cross-wave LDS
__global__ __launch_bounds__(SCAN_B) void scan1(const int* __restrict__ cnt,
                                                int* __restrict__ incl, int* __restrict__ bsum) {
    __shared__ int ws[16];
    int i = blockIdx.x * SCAN_B + threadIdx.x;
    int lane = threadIdx.x & 63, wid = threadIdx.x >> 6;
    int v = (i < N_NODES) ? cnt[i] : 0;
    int s = v;
    #pragma unroll
    for (int o = 1; o < 64; o <<= 1) {
        int t = __shfl_up(s, o, 64);
        if (lane >= o) s += t;
    }
    if (lane == 63) ws[wid] = s;
    __syncthreads();
    if (wid == 0) {
        int t = (lane < 16) ? ws[lane] : 0;
        #pragma unroll
        for (int o = 1; o < 16; o <<= 1) {
            int u = __shfl_up(t, o, 64);
            if (lane >= o) t += u;
        }
        if (lane < 16) ws[lane] = t;
    }
    __syncthreads();
    if (wid > 0) s += ws[wid - 1];
    if (i < N_NODES) incl[i] = s;
    if (threadIdx.x == SCAN_B - 1) bsum[blockIdx.x] = s;
}
__global__ void scan2(int* __restrict__ bsum, int nb) {
    __shared__ int sh[128];
    int v = (threadIdx.x < nb) ? bsum[threadIdx.x] : 0;
    sh[threadIdx.x] = v; __syncthreads();
    for (int off = 1; off < 128; off <<= 1) {
        int t = (threadIdx.x >= off) ? sh[threadIdx.x - off] : 0;
        __syncthreads();
        sh[threadIdx.x] += t;
        __syncthreads();
    }
    if (threadIdx.x < nb) bsum[threadIdx.x] = sh[threadIdx.x] - v;  // exclusive
}
__global__ void scan3(const int* __restrict__ cnt, const int* __restrict__ incl,
                      const int* __restrict__ bsum, int* __restrict__ off,
                      int* __restrict__ cursor) {
    int i = blockIdx.x * blockDim.x + threadIdx.x;
    if (i < N_NODES) {
        int v = incl[i] - cnt[i] + bsum[i / SCAN_B];
        off[i] = v; cursor[i] = v;
    }
    if (i == 0) off[N_NODES] = N_EDGES;
}
__global__ void fill_kernel(const int* __restrict__ src, const int* __restrict__ dst,
                            int* __restrict__ cursor, int* __restrict__ esrc) {
    int e = blockIdx.x * blockDim.x + threadIdx.x;
    if (e < N_EDGES) {
        int pos = atomicAdd(&cursor[dst[e]], 1);
        esrc[pos] = src[e];
    }
}

// ---------------- fused gather + MFMA GRU ----------------
// grid N_PAD/128; block 256 = 4 waves; wave: 32 rows.
// Phase 1: wave gathers its 32 aggr rows (2 x 16-row passes through per-wave
//          LDS scratch) -> av register fragments. LDS scratch aliases B buffer.
// Phase 2: r5-style jt loop: stage 43KB B tile to LDS, 12 MFMA x 7 kt, gates.
__global__ __launch_bounds__(256, 2) void gru_fused(const __hip_bfloat16* __restrict__ hcur,
                                                    __hip_bfloat16* __restrict__ hnext,
                                                    const int* __restrict__ off,
                                                    const int* __restrict__ esrc,
                                                    int step) {
    __shared__ short LDS[TILE_SHORTS];   // 43008 B; first 14336 shorts double as A scratch
    int tid = threadIdx.x;
    int lane = tid & 63, wave = tid >> 6;
    int wbase = blockIdx.x * 128 + wave * 32;    // first global row of this wave
    int mrow = lane & 15, kq = lane >> 4;

    short* Awave = LDS + wave * 16 * KP;         // 16 rows x 224 shorts per wave

    bfrag av[2][7], hv[2][7];

    // ---- gather: two 16-row phases ----
    int col = lane * 4;
    bool sum_l = (col < D);          // lanes 0..49 read/sum; 50..55 write zeros
    bool store_l = (lane < 56);
    #pragma unroll
    for (int p = 0; p < 2; ++p) {
        for (int r = 0; r < 16; ++r) {
            int n = wbase + p * 16 + r;
            float a0 = 0, a1 = 0, a2 = 0, a3 = 0;
            if (n < N_NODES && sum_l) {
                int e0 = off[n], e1 = off[n + 1];
                int e = e0;
                for (; e + 3 < e1; e += 4) {
                    const ushort4 v0 = *(const ushort4*)(hcur + (size_t)esrc[e] * KP + col);
                    const ushort4 v1 = *(const ushort4*)(hcur + (size_t)esrc[e + 1] * KP + col);
                    const ushort4 v2 = *(const ushort4*)(hcur + (size_t)esrc[e + 2] * KP + col);
                    const ushort4 v3 = *(const ushort4*)(hcur + (size_t)esrc[e + 3] * KP + col);
                    a0 += __bfloat162float(*(const __hip_bfloat16*)&v0.x) + __bfloat162float(*(const __hip_bfloat16*)&v1.x)
                        + __bfloat162float(*(const __hip_bfloat16*)&v2.x) + __bfloat162float(*(const __hip_bfloat16*)&v3.x);
                    a1 += __bfloat162float(*(const __hip_bfloat16*)&v0.y) + __bfloat162float(*(const __hip_bfloat16*)&v1.y)
                        + __bfloat162float(*(const __hip_bfloat16*)&v2.y) + __bfloat162float(*(const __hip_bfloat16*)&v3.y);
                    a2 += __bfloat162float(*(const __hip_bfloat16*)&v0.z) + __bfloat162float(*(const __hip_bfloat16*)&v1.z)
                        + __bfloat162float(*(const __hip_bfloat16*)&v2.z) + __bfloat162float(*(const __hip_bfloat16*)&v3.z);
                    a3 += __bfloat162float(*(const __hip_bfloat16*)&v0.w) + __bfloat162float(*(const __hip_bfloat16*)&v1.w)
                        + __bfloat162float(*(const __hip_bfloat16*)&v2.w) + __bfloat162float(*(const __hip_bfloat16*)&v3.w);
                }
                for (; e < e1; ++e) {
                    const ushort4 v = *(const ushort4*)(hcur + (size_t)esrc[e] * KP + col);
                    a0 += __bfloat162float(*(const __hip_bfloat16*)&v.x);
                    a1 += __bfloat162float(*(const __hip_bfloat16*)&v.y);
                    a2 += __bfloat162float(*(const __hip_bfloat16*)&v.z);
                    a3 += __bfloat162float(*(const __hip_bfloat16*)&v.w);
                }
            }
            if (store_l) {
                __hip_bfloat16 o[4];
                o[0] = __float2bfloat16(a0); o[1] = __float2bfloat16(a1);
                o[2] = __float2bfloat16(a2); o[3] = __float2bfloat16(a3);
                *(ushort4*)(Awave + r * KP + col) = *(const ushort4*)o;   // zeros in pad cols
            }
        }
        // read this phase's A fragments (own-wave LDS region only)
        #pragma unroll
        for (int t = 0; t < 7; ++t)
            av[p][t] = *(const bfrag*)&Awave[mrow * KP + t * 32 + kq * 8];
    }

    // ---- load this wave's H fragments from global (contiguous rows) ----
    size_t hbase = (size_t)(wbase + mrow) * KP + kq * 8;
    #pragma unroll
    for (int mf = 0; mf < 2; ++mf)
        #pragma unroll
        for (int t = 0; t < 7; ++t)
            hv[mf][t] = *(const bfrag*)(hcur + hbase + mf * 16 * KP + t * 32);

    const short* Wstep = g_Wall + (size_t)step * 13 * TILE_SHORTS;
    int jcol = lane & 15;
    int rowq = (lane >> 4) * 4;

    __syncthreads();   // all waves done with A scratch; LDS becomes B buffer

    for (int jt = 0; jt < 13; ++jt) {
        if (jt) __syncthreads();   // previous jt's B reads complete
        const short* Wtile = Wstep + (size_t)jt * TILE_SHORTS;
        #pragma unroll
        for (int i = 0; i < 11; ++i) {
            int c = i * 256 + tid;
            if (c < TILE_CHUNKS)
                *(bfrag*)&LDS[(size_t)c * 8] = *(const bfrag*)(Wtile + (size_t)c * 8);
        }
        __syncthreads();   // B tile visible

        facc acc[6][2];
        #pragma unroll
        for (int g = 0; g < 6; ++g)
            #pragma unroll
            for (int mf = 0; mf < 2; ++mf) acc[g][mf] = (facc)(0.0f);

        #pragma unroll
        for (int t = 0; t < 7; ++t) {
            bfrag bv[6];
            #pragma unroll
            for (int g = 0; g < 6; ++g)
                bv[g] = *(const bfrag*)&LDS[(size_t)(((g * 7 + t) * 64) + lane) * 8];
            #pragma unroll
            for (int g = 0; g < 3; ++g)
                #pragma unroll
                for (int mf = 0; mf < 2; ++mf) {
                    acc[g][mf]     = __builtin_amdgcn_mfma_f32_16x16x32_bf16(av[mf][t], bv[g],     acc[g][mf],     0, 0, 0);
                    acc[g + 3][mf] = __builtin_amdgcn_mfma_f32_16x16x32_bf16(hv[mf][t], bv[g + 3], acc[g + 3][mf], 0, 0, 0);
                }
        }

        // epilogue: C/D layout col=lane&15 (j), row=(lane>>4)*4+reg (m)
        int j = jt * 16 + jcol;
        if (j < D) {
            float bir = g_bias[j],          biz = g_bias[DP + j],     bin = g_bias[2 * DP + j];
            float bhr = g_bias[3 * DP + j], bhz = g_bias[4 * DP + j], bhn = g_bias[5 * DP + j];
            #pragma unroll
            for (int mf = 0; mf < 2; ++mf) {
                int m0 = wbase + mf * 16 + rowq;
                #pragma unroll
                for (int r = 0; r < 4; ++r) {
                    int m = m0 + r;
                    if (m < N_NODES) {
                        float hold = __bfloat162float(hcur[(size_t)m * KP + j]);
                        float rr = fast_sigmoid(acc[0][mf][r] + bir + acc[3][mf][r] + bhr);
                        float zz = fast_sigmoid(acc[1][mf][r] + biz + acc[4][mf][r] + bhz);
                        float nn = fast_tanh(acc[2][mf][r] + bin + rr * (acc[5][mf][r] + bhn));
                        hnext[(size_t)m * KP + j] = __float2bfloat16((1.0f - zz) * nn + zz * hold);
                    }
                }
            }
        }
    }
}

// ---------------- relu + column-max (bits trick, relu >= 0) ----------------
#define POOL_CHUNK 512
__global__ void pool_kernel(const __hip_bfloat16* __restrict__ h, unsigned int* __restrict__ pooled) {
    int d = threadIdx.x;
    if (d >= D) return;
    int n0 = blockIdx.x * POOL_CHUNK;
    float mx = 0.0f;
    for (int i = 0; i < POOL_CHUNK; ++i) {
        int n = n0 + i;
        if (n >= N_NODES) break;
        float v = __bfloat162float(h[(size_t)n * KP + d]);
        v = v > 0.0f ? v : 0.0f;
        mx = v > mx ? v : mx;
    }
    atomicMax(&pooled[d], __float_as_uint(mx));
}

// ---------------- logits + softmax ----------------
__global__ void head_kernel(const unsigned int* __restrict__ pooled,
                            const float* __restrict__ cls_w,
                            const float* __restrict__ cls_b,
                            float* __restrict__ out) {
    if (threadIdx.x == 0) {
        float l0 = cls_b[0], l1 = cls_b[1];
        for (int d = 0; d < D; ++d) {
            float p = __uint_as_float(pooled[d]);
            l0 += p * cls_w[d];
            l1 += p * cls_w[D + d];
        }
        float mx = l0 > l1 ? l0 : l1;
        float e0 = expf(l0 - mx), e1 = expf(l1 - mx);
        out[0] = e0 / (e0 + e1);
        out[1] = e1 / (e0 + e1);
    }
}

extern "C" void kernel_launch(void* const* d_in, const int* in_sizes, int n_in,
                              void* d_out, int out_size, void* d_ws, size_t ws_size,
                              hipStream_t stream) {
    const float* x     = (const float*)d_in[0];
    const float* W     = (const float*)d_in[1];
    const float* w_ih  = (const float*)d_in[2];
    const float* w_hh  = (const float*)d_in[3];
    const float* b_ih  = (const float*)d_in[4];
    const float* b_hh  = (const float*)d_in[5];
    const float* cls_w = (const float*)d_in[6];
    const float* cls_b = (const float*)d_in[7];
    const int*   ei    = (const int*)d_in[8];
    const int* src = ei;
    const int* dst = ei + N_EDGES;

    const size_t ROWB = (size_t)N_PAD * KP;     // bf16 elements per buffer
    __hip_bfloat16* hA   = (__hip_bfloat16*)d_ws;
    __hip_bfloat16* hB   = hA + ROWB;
    int* cnt    = (int*)(hB + ROWB);
    int* incl   = cnt + N_NODES;
    int* bsum   = incl + N_NODES;
    int* off    = bsum + 128;
    int* cursor = off + N_NODES + 1;
    int* esrc   = cursor + N_NODES;
    unsigned int* pooled = (unsigned int*)(esrc + N_EDGES);

    // CSR build (once per call; edges are step-invariant)
    hipMemsetAsync(cnt, 0, N_NODES * sizeof(int), stream);
    count_kernel<<<(N_EDGES + 255) / 256, 256, 0, stream>>>(dst, cnt);
    scan1<<<(N_NODES + SCAN_B - 1) / SCAN_B, SCAN_B, 0, stream>>>(cnt, incl, bsum);
    scan2<<<1, 128, 0, stream>>>(bsum, (N_NODES + SCAN_B - 1) / SCAN_B);
    scan3<<<(N_NODES + 255) / 256, 256, 0, stream>>>(cnt, incl, bsum, off, cursor);
    fill_kernel<<<(N_EDGES + 255) / 256, 256, 0, stream>>>(src, dst, cursor, esrc);

    // weight prep
    wc_kernel<<<NUM_STEPS * 600, 256, 0, stream>>>(W, w_ih);
    wconv_kernel<<<(NUM_STEPS * 13 * 6 * 7 * 64) / 256, 256, 0, stream>>>(w_hh);
    bias_kernel<<<(6 * DP + 255) / 256, 256, 0, stream>>>(b_ih, b_hh);

    pad_kernel<<<(int)(ROWB / 256), 256, 0, stream>>>(x, hA);

    __hip_bfloat16* hcur = hA;
    __hip_bfloat16* hnext = hB;
    for (int s = 0; s < NUM_STEPS; ++s) {
        gru_fused<<<N_PAD / 128, 256, 0, stream>>>(hcur, hnext, off, esrc, s);
        __hip_bfloat16* t = hcur; hcur = hnext; hnext = t;
    }
    hipMemsetAsync(pooled, 0, D * sizeof(unsigned int), stream);
    pool_kernel<<<(N_NODES + POOL_CHUNK - 1) / POOL_CHUNK, 256, 0, stream>>>(hcur, pooled);
    head_kernel<<<1, 64, 0, stream>>>(pooled, cls_w, cls_b, (float*)d_out);
}

// Round 9
// 962.092 us; speedup vs baseline: 1.3905x; 1.3187x over previous
//
#include <hip/hip_runtime.h>
#include <hip/hip_bf16.h>
#include <math.h>

#define N_NODES 100000
#define N_PAD   100096   // multiple of 256
#define N_EDGES 400000
#define IN_DIM  100
#define D       200
#define DP      208      // j padded to 13*16
#define KP      224      // k padded to 7*32
#define NUM_STEPS 4

#define TILE_CHUNKS 2688           // 6 gates * 7 kt * 64 lanes, 16B each = 43008 B
#define TILE_SHORTS (TILE_CHUNKS * 8)

typedef __attribute__((ext_vector_type(8))) short bfrag;   // 8 bf16 (4 VGPRs)
typedef __attribute__((ext_vector_type(4))) float facc;    // 4 fp32

// Wc[s] = w_ih @ W[s]^T so that gi = aggr_raw @ Wc[s]^T  (scatter is linear)
__device__ float g_Wc[NUM_STEPS * 600 * D];
// weights, per-(step,jt) CONTIGUOUS tile: [s][jt][g6][t7][lane64][8]
__device__ short g_Wall[NUM_STEPS * 13 * TILE_SHORTS];
__device__ float g_bias[6 * DP];

__device__ __forceinline__ float fast_sigmoid(float x) {
    return __builtin_amdgcn_rcpf(1.0f + __expf(-x));
}
__device__ __forceinline__ float fast_tanh(float x) {
    return 2.0f * __builtin_amdgcn_rcpf(1.0f + __expf(-2.0f * x)) - 1.0f;
}
__device__ __forceinline__ float bf2f(short u) {
    unsigned int x = ((unsigned int)(unsigned short)u) << 16;
    return __uint_as_float(x);
}

// ---------------- Wc precompute: block=(s*600+j), thread=k ----------------
__global__ __launch_bounds__(256) void wc_kernel(const float* __restrict__ W,
                                                 const float* __restrict__ w_ih) {
    int s = blockIdx.x / 600;
    int j = blockIdx.x % 600;
    int k = threadIdx.x;
    if (k >= D) return;
    const float* wr = &w_ih[(size_t)j * D];
    const float* Wr = &W[(size_t)s * D * D + (size_t)k * D];
    float acc = 0.0f;
    #pragma unroll 4
    for (int t = 0; t < D; ++t) acc += wr[t] * Wr[t];
    g_Wc[((size_t)s * 600 + j) * D + k] = acc;
}

// ---------------- permute weights into per-tile fragment order (bf16) ----------------
// output idx = (((s*13 + jt)*6 + g)*7 + t)*64 + l, 8 shorts each
__global__ __launch_bounds__(256) void wconv_kernel(const float* __restrict__ w_hh) {
    int idx = blockIdx.x * 256 + threadIdx.x;   // < 4*13*6*7*64 = 139776
    int l  = idx & 63;
    int t  = (idx >> 6) % 7;
    int g  = (idx / 448) % 6;
    int jt = (idx / 2688) % 13;
    int s  = idx / 34944;
    int j  = jt * 16 + (l & 15);
    int k0 = t * 32 + (l >> 4) * 8;
    short* out = g_Wall + (size_t)idx * 8;
    #pragma unroll
    for (int i = 0; i < 8; ++i) {
        int k = k0 + i;
        float v = 0.0f;
        if (j < D && k < D)
            v = (g < 3) ? g_Wc[((size_t)s * 600 + g * 200 + j) * D + k]
                        : w_hh[((size_t)(g - 3) * 200 + j) * D + k];
        __hip_bfloat16 b = __float2bfloat16(v);
        out[i] = *reinterpret_cast<short*>(&b);
    }
}

__global__ void bias_kernel(const float* __restrict__ b_ih, const float* __restrict__ b_hh) {
    int idx = blockIdx.x * 256 + threadIdx.x;
    if (idx >= 6 * DP) return;
    int g = idx / DP, j = idx % DP;
    float v = 0.0f;
    if (j < D) v = (g < 3) ? b_ih[g * 200 + j] : b_hh[(g - 3) * 200 + j];
    g_bias[idx] = v;
}

// ---------------- pad: h[:, :100] = bf16(x), rest 0 ----------------
__global__ void pad_kernel(const float* __restrict__ x, __hip_bfloat16* __restrict__ h) {
    int idx = blockIdx.x * 256 + threadIdx.x;   // N_PAD*KP exact multiple of 256
    int n = idx / KP, c = idx % KP;
    float v = (n < N_NODES && c < IN_DIM) ? x[n * IN_DIM + c] : 0.0f;
    h[idx] = __float2bfloat16(v);
}

// ---------------- CSR build ----------------
__global__ void count_kernel(const int* __restrict__ dst, int* __restrict__ cnt) {
    int e = blockIdx.x * blockDim.x + threadIdx.x;
    if (e < N_EDGES) atomicAdd(&cnt[dst[e]], 1);
}

#define SCAN_B 1024
// 2-barrier block scan: wave shuffle-scan + cross-wave LDS
__global__ __launch_bounds__(SCAN_B) void scan1(const int* __restrict__ cnt,
                                                int* __restrict__ incl, int* __restrict__ bsum) {
    __shared__ int ws[16];
    int i = blockIdx.x * SCAN_B + threadIdx.x;
    int lane = threadIdx.x & 63, wid = threadIdx.x >> 6;
    int v = (i < N_NODES) ? cnt[i] : 0;
    int s = v;
    #pragma unroll
    for (int o = 1; o < 64; o <<= 1) {
        int t = __shfl_up(s, o, 64);
        if (lane >= o) s += t;
    }
    if (lane == 63) ws[wid] = s;
    __syncthreads();
    if (wid == 0) {
        int t = (lane < 16) ? ws[lane] : 0;
        #pragma unroll
        for (int o = 1; o < 16; o <<= 1) {
            int u = __shfl_up(t, o, 64);
            if (lane >= o) t += u;
        }
        if (lane < 16) ws[lane] = t;
    }
    __syncthreads();
    if (wid > 0) s += ws[wid - 1];
    if (i < N_NODES) incl[i] = s;
    if (threadIdx.x == SCAN_B - 1) bsum[blockIdx.x] = s;
}
__global__ void scan2(int* __restrict__ bsum, int nb) {
    __shared__ int sh[128];
    int v = (threadIdx.x < nb) ? bsum[threadIdx.x] : 0;
    sh[threadIdx.x] = v; __syncthreads();
    for (int off = 1; off < 128; off <<= 1) {
        int t = (threadIdx.x >= off) ? sh[threadIdx.x - off] : 0;
        __syncthreads();
        sh[threadIdx.x] += t;
        __syncthreads();
    }
    if (threadIdx.x < nb) bsum[threadIdx.x] = sh[threadIdx.x] - v;  // exclusive
}
__global__ void scan3(const int* __restrict__ cnt, const int* __restrict__ incl,
                      const int* __restrict__ bsum, int* __restrict__ off,
                      int* __restrict__ cursor) {
    int i = blockIdx.x * blockDim.x + threadIdx.x;
    if (i < N_NODES) {
        int v = incl[i] - cnt[i] + bsum[i / SCAN_B];
        off[i] = v; cursor[i] = v;
    }
    if (i == 0) off[N_NODES] = N_EDGES;
}
__global__ void fill_kernel(const int* __restrict__ src, const int* __restrict__ dst,
                            int* __restrict__ cursor, int* __restrict__ esrc) {
    int e = blockIdx.x * blockDim.x + threadIdx.x;
    if (e < N_EDGES) {
        int pos = atomicAdd(&cursor[dst[e]], 1);
        esrc[pos] = src[e];
    }
}

// ---------------- async stage: one jt tile (43008 B) global -> LDS ----------------
__device__ __forceinline__ void stage_tile(const short* __restrict__ gsrc,
                                           short* lds_dst, int wave, int lane) {
    // 42 wave-groups of 64 chunks x 16B; wave-uniform LDS base + lane*16
    for (int g = wave; g < 42; g += 4) {
        __builtin_amdgcn_global_load_lds(
            (const __attribute__((address_space(1))) void*)(gsrc + g * 512 + lane * 8),
            (__attribute__((address_space(3))) void*)(lds_dst + g * 512),
            16, 0, 0);
    }
}

// ---------------- fused gather + MFMA GRU (+ pool on last step) ----------------
// grid N_PAD/128; block 256 = 4 waves; wave: 32 rows.
// Phase 1: wave gathers its 32 aggr rows, 2 rows in parallel (28 lanes x 16B each),
//          through per-wave LDS scratch -> av register fragments.
// Phase 2: jt loop: DMA-stage 43KB B tile to LDS, hold preload, 12 MFMA x 7 kt, gates.
// step==3: relu+col-max pooled via LDS bit-max + global atomicMax.
__global__ __launch_bounds__(256, 2) void gru_fused(const __hip_bfloat16* __restrict__ hcur,
                                                    __hip_bfloat16* __restrict__ hnext,
                                                    const int* __restrict__ off,
                                                    const int* __restrict__ esrc,
                                                    unsigned int* __restrict__ pooled,
                                                    int step) {
    __shared__ short LDS[TILE_SHORTS];   // 43008 B; first 28672 B double as A scratch
    __shared__ unsigned int pmax[DP];    // step-3 pooling scratch (bits of relu'd fp32)
    int tid = threadIdx.x;
    int lane = tid & 63, wave = tid >> 6;
    int wbase = blockIdx.x * 128 + wave * 32;    // first global row of this wave
    int mrow = lane & 15, kq = lane >> 4;
    bool dopool = (step == NUM_STEPS - 1);

    if (dopool) for (int c = tid; c < DP; c += 256) pmax[c] = 0u;

    short* Awave = LDS + wave * 16 * KP;         // 16 rows x 224 shorts per wave

    bfrag av[2][7], hv[2][7];

    // ---- gather: 2 phases x 16 rows; 2 rows in parallel per wave ----
    int rg = lane / 28;              // 0 or 1 (lanes 56..63 idle)
    int cl = lane % 28;              // 16B col-group
    int col = cl * 8;                // shorts
    bool active = (rg < 2);
    bool sum_l  = active && (cl < 25);   // cols 0..199 carry data
    #pragma unroll
    for (int p = 0; p < 2; ++p) {
        for (int it = 0; it < 8; ++it) {
            int r = it * 2 + rg;             // row within phase
            int n = wbase + p * 16 + r;
            float a[8] = {0, 0, 0, 0, 0, 0, 0, 0};
            if (sum_l && n < N_NODES) {
                int e0 = off[n], e1 = off[n + 1];
                int e = e0;
                for (; e + 1 < e1; e += 2) {
                    bfrag v0 = *(const bfrag*)(hcur + (size_t)esrc[e] * KP + col);
                    bfrag v1 = *(const bfrag*)(hcur + (size_t)esrc[e + 1] * KP + col);
                    #pragma unroll
                    for (int q = 0; q < 8; ++q)
                        a[q] += bf2f(v0[q]) + bf2f(v1[q]);
                }
                if (e < e1) {
                    bfrag v0 = *(const bfrag*)(hcur + (size_t)esrc[e] * KP + col);
                    #pragma unroll
                    for (int q = 0; q < 8; ++q)
                        a[q] += bf2f(v0[q]);
                }
            }
            if (active) {
                __hip_bfloat16 o[8];
                #pragma unroll
                for (int q = 0; q < 8; ++q) o[q] = __float2bfloat16(a[q]);
                // two 8B stores (bank-friendly)
                *(ushort4*)(Awave + r * KP + col)     = *(const ushort4*)&o[0];
                *(ushort4*)(Awave + r * KP + col + 4) = *(const ushort4*)&o[4];
            }
        }
        // read this phase's A fragments (own-wave LDS region only)
        #pragma unroll
        for (int t = 0; t < 7; ++t)
            av[p][t] = *(const bfrag*)&Awave[mrow * KP + t * 32 + kq * 8];
    }

    // ---- load this wave's H fragments from global (contiguous rows) ----
    size_t hbase = (size_t)(wbase + mrow) * KP + kq * 8;
    #pragma unroll
    for (int mf = 0; mf < 2; ++mf)
        #pragma unroll
        for (int t = 0; t < 7; ++t)
            hv[mf][t] = *(const bfrag*)(hcur + hbase + mf * 16 * KP + t * 32);

    const short* Wstep = g_Wall + (size_t)step * 13 * TILE_SHORTS;
    int jcol = lane & 15;
    int rowq = (lane >> 4) * 4;

    __syncthreads();   // all waves done with A scratch (and pmax init); LDS becomes B buffer

    for (int jt = 0; jt < 13; ++jt) {
        // DMA-stage this jt's B tile (no VGPR round-trip)
        stage_tile(Wstep + (size_t)jt * TILE_SHORTS, &LDS[0], wave, lane);

        int j = jt * 16 + jcol;
        // preload old-h for epilogue (always in-bounds: j < 224, rows < N_PAD)
        unsigned short hold_u[2][4];
        #pragma unroll
        for (int mf = 0; mf < 2; ++mf)
            #pragma unroll
            for (int r = 0; r < 4; ++r)
                hold_u[mf][r] = *(const unsigned short*)
                    (hcur + (size_t)(wbase + mf * 16 + rowq + r) * KP + j);

        __syncthreads();   // drains vmcnt: B tile staged (hold also landed)

        facc acc[6][2];
        #pragma unroll
        for (int g = 0; g < 6; ++g)
            #pragma unroll
            for (int mf = 0; mf < 2; ++mf) acc[g][mf] = (facc)(0.0f);

        #pragma unroll
        for (int t = 0; t < 7; ++t) {
            bfrag bv[6];
            #pragma unroll
            for (int g = 0; g < 6; ++g)
                bv[g] = *(const bfrag*)&LDS[(size_t)(((g * 7 + t) * 64) + lane) * 8];
            #pragma unroll
            for (int g = 0; g < 3; ++g)
                #pragma unroll
                for (int mf = 0; mf < 2; ++mf) {
                    acc[g][mf]     = __builtin_amdgcn_mfma_f32_16x16x32_bf16(av[mf][t], bv[g],     acc[g][mf],     0, 0, 0);
                    acc[g + 3][mf] = __builtin_amdgcn_mfma_f32_16x16x32_bf16(hv[mf][t], bv[g + 3], acc[g + 3][mf], 0, 0, 0);
                }
        }

        // epilogue: C/D layout col=lane&15 (j), row=(lane>>4)*4+reg (m)
        float tmax = 0.0f;
        if (j < D) {
            float bir = g_bias[j],          biz = g_bias[DP + j],     bin = g_bias[2 * DP + j];
            float bhr = g_bias[3 * DP + j], bhz = g_bias[4 * DP + j], bhn = g_bias[5 * DP + j];
            #pragma unroll
            for (int mf = 0; mf < 2; ++mf) {
                int m0 = wbase + mf * 16 + rowq;
                #pragma unroll
                for (int r = 0; r < 4; ++r) {
                    int m = m0 + r;
                    if (m < N_NODES) {
                        float hold = bf2f((short)hold_u[mf][r]);
                        float rr = fast_sigmoid(acc[0][mf][r] + bir + acc[3][mf][r] + bhr);
                        float zz = fast_sigmoid(acc[1][mf][r] + biz + acc[4][mf][r] + bhz);
                        float nn = fast_tanh(acc[2][mf][r] + bin + rr * (acc[5][mf][r] + bhn));
                        float hv2 = (1.0f - zz) * nn + zz * hold;
                        hnext[(size_t)m * KP + j] = __float2bfloat16(hv2);
                        if (hv2 > tmax) tmax = hv2;   // relu'd max (tmax >= 0)
                    }
                }
            }
            if (dopool) atomicMax(&pmax[j], __float_as_uint(tmax));
        }
        __syncthreads();   // B reads done; safe to re-stage next jt
    }

    if (dopool) {
        // one global atomic per column per block
        for (int c = tid; c < D; c += 256) atomicMax(&pooled[c], pmax[c]);
    }
}

// ---------------- logits + softmax ----------------
__global__ void head_kernel(const unsigned int* __restrict__ pooled,
                            const float* __restrict__ cls_w,
                            const float* __restrict__ cls_b,
                            float* __restrict__ out) {
    if (threadIdx.x == 0) {
        float l0 = cls_b[0], l1 = cls_b[1];
        for (int d = 0; d < D; ++d) {
            float p = __uint_as_float(pooled[d]);
            l0 += p * cls_w[d];
            l1 += p * cls_w[D + d];
        }
        float mx = l0 > l1 ? l0 : l1;
        float e0 = expf(l0 - mx), e1 = expf(l1 - mx);
        out[0] = e0 / (e0 + e1);
        out[1] = e1 / (e0 + e1);
    }
}

extern "C" void kernel_launch(void* const* d_in, const int* in_sizes, int n_in,
                              void* d_out, int out_size, void* d_ws, size_t ws_size,
                              hipStream_t stream) {
    const float* x     = (const float*)d_in[0];
    const float* W     = (const float*)d_in[1];
    const float* w_ih  = (const float*)d_in[2];
    const float* w_hh  = (const float*)d_in[3];
    const float* b_ih  = (const float*)d_in[4];
    const float* b_hh  = (const float*)d_in[5];
    const float* cls_w = (const float*)d_in[6];
    const float* cls_b = (const float*)d_in[7];
    const int*   ei    = (const int*)d_in[8];
    const int* src = ei;
    const int* dst = ei + N_EDGES;

    const size_t ROWB = (size_t)N_PAD * KP;     // bf16 elements per buffer
    __hip_bfloat16* hA   = (__hip_bfloat16*)d_ws;
    __hip_bfloat16* hB   = hA + ROWB;
    int* cnt    = (int*)(hB + ROWB);
    int* incl   = cnt + N_NODES;
    int* bsum   = incl + N_NODES;
    int* off    = bsum + 128;
    int* cursor = off + N_NODES + 1;
    int* esrc   = cursor + N_NODES;
    unsigned int* pooled = (unsigned int*)(esrc + N_EDGES);

    // CSR build (once per call; edges are step-invariant)
    hipMemsetAsync(cnt, 0, N_NODES * sizeof(int), stream);
    count_kernel<<<(N_EDGES + 255) / 256, 256, 0, stream>>>(dst, cnt);
    scan1<<<(N_NODES + SCAN_B - 1) / SCAN_B, SCAN_B, 0, stream>>>(cnt, incl, bsum);
    scan2<<<1, 128, 0, stream>>>(bsum, (N_NODES + SCAN_B - 1) / SCAN_B);
    scan3<<<(N_NODES + 255) / 256, 256, 0, stream>>>(cnt, incl, bsum, off, cursor);
    fill_kernel<<<(N_EDGES + 255) / 256, 256, 0, stream>>>(src, dst, cursor, esrc);

    // weight prep
    wc_kernel<<<NUM_STEPS * 600, 256, 0, stream>>>(W, w_ih);
    wconv_kernel<<<(NUM_STEPS * 13 * 6 * 7 * 64) / 256, 256, 0, stream>>>(w_hh);
    bias_kernel<<<(6 * DP + 255) / 256, 256, 0, stream>>>(b_ih, b_hh);

    pad_kernel<<<(int)(ROWB / 256), 256, 0, stream>>>(x, hA);
    hipMemsetAsync(pooled, 0, D * sizeof(unsigned int), stream);

    __hip_bfloat16* hcur = hA;
    __hip_bfloat16* hnext = hB;
    for (int s = 0; s < NUM_STEPS; ++s) {
        gru_fused<<<N_PAD / 128, 256, 0, stream>>>(hcur, hnext, off, esrc, pooled, s);
        __hip_bfloat16* t = hcur; hcur = hnext; hnext = t;
    }
    head_kernel<<<1, 64, 0, stream>>>(pooled, cls_w, cls_b, (float*)d_out);
}

// Round 10
// 892.702 us; speedup vs baseline: 1.4986x; 1.0777x over previous
//
#include <hip/hip_runtime.h>
#include <hip/hip_bf16.h>
#include <math.h>

#define N_NODES 100000
#define N_PAD   100096   // multiple of 256
#define N_EDGES 400000
#define IN_DIM  100
#define D       200
#define DP      208      // j padded to 13*16
#define KP      224      // k padded to 7*32
#define NUM_STEPS 4

#define TILE_SHORTS  21504         // full jt tile: 6 gates * 7 kt * 64 lanes * 8 shorts
#define HALF_SHORTS  10752         // 3 gates
#define HALF_GROUPS  21            // 1344 chunks / 64 lanes

typedef __attribute__((ext_vector_type(8))) short bfrag;   // 8 bf16 (4 VGPRs)
typedef __attribute__((ext_vector_type(4))) float facc;    // 4 fp32

// Wc[s] = w_ih @ W[s]^T so that gi = aggr_raw @ Wc[s]^T  (scatter is linear)
__device__ float g_Wc[NUM_STEPS * 600 * D];
// weights, per-(step,jt) CONTIGUOUS tile: [s][jt][g6][t7][lane64][8]
__device__ short g_Wall[NUM_STEPS * 13 * TILE_SHORTS];
__device__ float g_bias[6 * DP];

__device__ __forceinline__ float fast_sigmoid(float x) {
    return __builtin_amdgcn_rcpf(1.0f + __expf(-x));
}
__device__ __forceinline__ float fast_tanh(float x) {
    return 2.0f * __builtin_amdgcn_rcpf(1.0f + __expf(-2.0f * x)) - 1.0f;
}
__device__ __forceinline__ float bf2f(short u) {
    unsigned int x = ((unsigned int)(unsigned short)u) << 16;
    return __uint_as_float(x);
}

// ---------------- Wc precompute: block=(s*600+j), thread=k ----------------
__global__ __launch_bounds__(256) void wc_kernel(const float* __restrict__ W,
                                                 const float* __restrict__ w_ih) {
    int s = blockIdx.x / 600;
    int j = blockIdx.x % 600;
    int k = threadIdx.x;
    if (k >= D) return;
    const float* wr = &w_ih[(size_t)j * D];
    const float* Wr = &W[(size_t)s * D * D + (size_t)k * D];
    float acc = 0.0f;
    #pragma unroll 4
    for (int t = 0; t < D; ++t) acc += wr[t] * Wr[t];
    g_Wc[((size_t)s * 600 + j) * D + k] = acc;
}

// ---------------- permute weights into per-tile fragment order (bf16) ----------------
// output idx = (((s*13 + jt)*6 + g)*7 + t)*64 + l, 8 shorts each
__global__ __launch_bounds__(256) void wconv_kernel(const float* __restrict__ w_hh) {
    int idx = blockIdx.x * 256 + threadIdx.x;   // < 4*13*6*7*64 = 139776
    int l  = idx & 63;
    int t  = (idx >> 6) % 7;
    int g  = (idx / 448) % 6;
    int jt = (idx / 2688) % 13;
    int s  = idx / 34944;
    int j  = jt * 16 + (l & 15);
    int k0 = t * 32 + (l >> 4) * 8;
    short* out = g_Wall + (size_t)idx * 8;
    #pragma unroll
    for (int i = 0; i < 8; ++i) {
        int k = k0 + i;
        float v = 0.0f;
        if (j < D && k < D)
            v = (g < 3) ? g_Wc[((size_t)s * 600 + g * 200 + j) * D + k]
                        : w_hh[((size_t)(g - 3) * 200 + j) * D + k];
        __hip_bfloat16 b = __float2bfloat16(v);
        out[i] = *reinterpret_cast<short*>(&b);
    }
}

__global__ void bias_kernel(const float* __restrict__ b_ih, const float* __restrict__ b_hh) {
    int idx = blockIdx.x * 256 + threadIdx.x;
    if (idx >= 6 * DP) return;
    int g = idx / DP, j = idx % DP;
    float v = 0.0f;
    if (j < D) v = (g < 3) ? b_ih[g * 200 + j] : b_hh[(g - 3) * 200 + j];
    g_bias[idx] = v;
}

// ---------------- pad: h[:, :100] = bf16(x), rest 0 ----------------
__global__ void pad_kernel(const float* __restrict__ x, __hip_bfloat16* __restrict__ h) {
    int idx = blockIdx.x * 256 + threadIdx.x;   // N_PAD*KP exact multiple of 256
    int n = idx / KP, c = idx % KP;
    float v = (n < N_NODES && c < IN_DIM) ? x[n * IN_DIM + c] : 0.0f;
    h[idx] = __float2bfloat16(v);
}

// ---------------- CSR build ----------------
__global__ void count_kernel(const int* __restrict__ dst, int* __restrict__ cnt) {
    int e = blockIdx.x * blockDim.x + threadIdx.x;
    if (e < N_EDGES) atomicAdd(&cnt[dst[e]], 1);
}

#define SCAN_B 1024
// 2-barrier block scan: wave shuffle-scan + cross-wave LDS
__global__ __launch_bounds__(SCAN_B) void scan1(const int* __restrict__ cnt,
                                                int* __restrict__ incl, int* __restrict__ bsum) {
    __shared__ int ws[16];
    int i = blockIdx.x * SCAN_B + threadIdx.x;
    int lane = threadIdx.x & 63, wid = threadIdx.x >> 6;
    int v = (i < N_NODES) ? cnt[i] : 0;
    int s = v;
    #pragma unroll
    for (int o = 1; o < 64; o <<= 1) {
        int t = __shfl_up(s, o, 64);
        if (lane >= o) s += t;
    }
    if (lane == 63) ws[wid] = s;
    __syncthreads();
    if (wid == 0) {
        int t = (lane < 16) ? ws[lane] : 0;
        #pragma unroll
        for (int o = 1; o < 16; o <<= 1) {
            int u = __shfl_up(t, o, 64);
            if (lane >= o) t += u;
        }
        if (lane < 16) ws[lane] = t;
    }
    __syncthreads();
    if (wid > 0) s += ws[wid - 1];
    if (i < N_NODES) incl[i] = s;
    if (threadIdx.x == SCAN_B - 1) bsum[blockIdx.x] = s;
}
__global__ void scan2(int* __restrict__ bsum, int nb) {
    __shared__ int sh[128];
    int v = (threadIdx.x < nb) ? bsum[threadIdx.x] : 0;
    sh[threadIdx.x] = v; __syncthreads();
    for (int off = 1; off < 128; off <<= 1) {
        int t = (threadIdx.x >= off) ? sh[threadIdx.x - off] : 0;
        __syncthreads();
        sh[threadIdx.x] += t;
        __syncthreads();
    }
    if (threadIdx.x < nb) bsum[threadIdx.x] = sh[threadIdx.x] - v;  // exclusive
}
__global__ void scan3(const int* __restrict__ cnt, const int* __restrict__ incl,
                      const int* __restrict__ bsum, int* __restrict__ off,
                      int* __restrict__ cursor) {
    int i = blockIdx.x * blockDim.x + threadIdx.x;
    if (i < N_NODES) {
        int v = incl[i] - cnt[i] + bsum[i / SCAN_B];
        off[i] = v; cursor[i] = v;
    }
    if (i == 0) off[N_NODES] = N_EDGES;
}
__global__ void fill_kernel(const int* __restrict__ src, const int* __restrict__ dst,
                            int* __restrict__ cursor, int* __restrict__ esrc) {
    int e = blockIdx.x * blockDim.x + threadIdx.x;
    if (e < N_EDGES) {
        int pos = atomicAdd(&cursor[dst[e]], 1);
        esrc[pos] = src[e];
    }
}

// ---------------- async stage: one HALF tile (21504 B) global -> LDS ----------------
__device__ __forceinline__ void stage_half(const short* __restrict__ gsrc,
                                           short* lds_dst, int wave, int lane) {
    #pragma unroll
    for (int g = wave; g < HALF_GROUPS; g += 4) {
        __builtin_amdgcn_global_load_lds(
            (const __attribute__((address_space(1))) void*)(gsrc + g * 512 + lane * 8),
            (__attribute__((address_space(3))) void*)(lds_dst + g * 512),
            16, 0, 0);
    }
}

// ---------------- fused gather + MFMA GRU (+ pool on last step) ----------------
// grid N_PAD/128; block 256 = 4 waves; wave: 32 rows.
// Phase 1: gather 32 aggr rows, 4 rows in flight (16 lanes x 1-2 16B chunks each),
//          via per-wave LDS scratch -> av register fragments.
// Phase 2: 26 half-tile iterations, double-buffered DMA: barrier; issue DMA of
//          half k+1; compute half k (gi-gates with av / gh-gates with hv);
//          epilogue+gates on odd halves.  LDS = 2 x 21.5 KB (3 blocks/CU kept).
__global__ __launch_bounds__(256, 2) void gru_fused(const __hip_bfloat16* __restrict__ hcur,
                                                    __hip_bfloat16* __restrict__ hnext,
                                                    const int* __restrict__ off,
                                                    const int* __restrict__ esrc,
                                                    unsigned int* __restrict__ pooled,
                                                    int step) {
    __shared__ short Bs[2][HALF_SHORTS];  // 43008 B total; also aliased as A-scratch
    __shared__ unsigned int pmax[DP];     // step-3 pooling scratch
    int tid = threadIdx.x;
    int lane = tid & 63, wave = tid >> 6;
    int wbase = blockIdx.x * 128 + wave * 32;
    int mrow = lane & 15, kq = lane >> 4;
    bool dopool = (step == NUM_STEPS - 1);

    if (dopool) for (int c = tid; c < DP; c += 256) pmax[c] = 0u;

    short* LDSbase = &Bs[0][0];
    short* Awave = LDSbase + wave * 16 * KP;   // 16 rows x 224 shorts per wave

    bfrag av[2][7], hv[2][7];

    // ---- gather: 2 phases x 16 rows; 4 rows in flight per wave ----
    int r4 = lane >> 4;              // row-in-flight 0..3
    int ck = lane & 15;              // 16B chunk id (this lane also covers ck+16)
    int colA = ck * 8;
    int colB = colA + 128;           // (ck+16)*8
    bool sumB = (ck < 9);            // chunks 16..24 carry data (cols < 200)
    #pragma unroll
    for (int p = 0; p < 2; ++p) {
        #pragma unroll
        for (int it = 0; it < 4; ++it) {
            int rr = it * 4 + r4;            // row within phase
            int n = wbase + p * 16 + rr;
            float a[8] = {0, 0, 0, 0, 0, 0, 0, 0};
            float b[8] = {0, 0, 0, 0, 0, 0, 0, 0};
            if (n < N_NODES) {
                int e0 = off[n], e1 = off[n + 1];
                int e = e0;
                for (; e + 1 < e1; e += 2) {
                    size_t s0 = (size_t)esrc[e] * KP;
                    size_t s1 = (size_t)esrc[e + 1] * KP;
                    bfrag va0 = *(const bfrag*)(hcur + s0 + colA);
                    bfrag va1 = *(const bfrag*)(hcur + s1 + colA);
                    if (sumB) {
                        bfrag vb0 = *(const bfrag*)(hcur + s0 + colB);
                        bfrag vb1 = *(const bfrag*)(hcur + s1 + colB);
                        #pragma unroll
                        for (int q = 0; q < 8; ++q)
                            b[q] += bf2f(vb0[q]) + bf2f(vb1[q]);
                    }
                    #pragma unroll
                    for (int q = 0; q < 8; ++q)
                        a[q] += bf2f(va0[q]) + bf2f(va1[q]);
                }
                if (e < e1) {
                    size_t s0 = (size_t)esrc[e] * KP;
                    bfrag va0 = *(const bfrag*)(hcur + s0 + colA);
                    if (sumB) {
                        bfrag vb0 = *(const bfrag*)(hcur + s0 + colB);
                        #pragma unroll
                        for (int q = 0; q < 8; ++q) b[q] += bf2f(vb0[q]);
                    }
                    #pragma unroll
                    for (int q = 0; q < 8; ++q) a[q] += bf2f(va0[q]);
                }
            }
            __hip_bfloat16 oa[8], ob[8];
            #pragma unroll
            for (int q = 0; q < 8; ++q) {
                oa[q] = __float2bfloat16(a[q]);
                ob[q] = __float2bfloat16(b[q]);
            }
            *(ushort4*)(Awave + rr * KP + colA)     = *(const ushort4*)&oa[0];
            *(ushort4*)(Awave + rr * KP + colA + 4) = *(const ushort4*)&oa[4];
            if (ck < 12) {   // chunks 16..27 (25..27 are zero pads; b stayed 0)
                *(ushort4*)(Awave + rr * KP + colB)     = *(const ushort4*)&ob[0];
                *(ushort4*)(Awave + rr * KP + colB + 4) = *(const ushort4*)&ob[4];
            }
        }
        // read this phase's A fragments (own-wave LDS region only)
        #pragma unroll
        for (int t = 0; t < 7; ++t)
            av[p][t] = *(const bfrag*)&Awave[mrow * KP + t * 32 + kq * 8];
    }

    // ---- load this wave's H fragments from global (contiguous rows) ----
    size_t hbase = (size_t)(wbase + mrow) * KP + kq * 8;
    #pragma unroll
    for (int mf = 0; mf < 2; ++mf)
        #pragma unroll
        for (int t = 0; t < 7; ++t)
            hv[mf][t] = *(const bfrag*)(hcur + hbase + mf * 16 * KP + t * 32);

    const short* Wstep = g_Wall + (size_t)step * 13 * TILE_SHORTS;
    int jcol = lane & 15;
    int rowq = (lane >> 4) * 4;

    __syncthreads();                       // A-scratch reads complete; LDS -> B buffers
    stage_half(Wstep, &Bs[0][0], wave, lane);   // h0 = (jt0, gi-gates)

    facc acc[6][2];
    unsigned short hold_u[2][4];

    for (int hk = 0; hk < 26; ++hk) {
        __syncthreads();   // h_hk DMA complete; buf[(hk+1)&1] free for restage
        if (hk + 1 < 26)
            stage_half(Wstep + (size_t)(hk + 1) * HALF_SHORTS,
                       &Bs[(hk + 1) & 1][0], wave, lane);

        int jt = hk >> 1;
        int j = jt * 16 + jcol;
        const short* Bcur = &Bs[hk & 1][0];

        if ((hk & 1) == 0) {
            // preload old-h for this jt's epilogue (latency hides under both halves)
            #pragma unroll
            for (int mf = 0; mf < 2; ++mf)
                #pragma unroll
                for (int r = 0; r < 4; ++r)
                    hold_u[mf][r] = *(const unsigned short*)
                        (hcur + (size_t)(wbase + mf * 16 + rowq + r) * KP + j);
            #pragma unroll
            for (int g = 0; g < 6; ++g)
                #pragma unroll
                for (int mf = 0; mf < 2; ++mf) acc[g][mf] = (facc)(0.0f);
            // gi gates (0..2) consume av
            #pragma unroll
            for (int t = 0; t < 7; ++t) {
                bfrag bv[3];
                #pragma unroll
                for (int g = 0; g < 3; ++g)
                    bv[g] = *(const bfrag*)&Bcur[(size_t)(((g * 7 + t) * 64) + lane) * 8];
                #pragma unroll
                for (int g = 0; g < 3; ++g)
                    #pragma unroll
                    for (int mf = 0; mf < 2; ++mf)
                        acc[g][mf] = __builtin_amdgcn_mfma_f32_16x16x32_bf16(av[mf][t], bv[g], acc[g][mf], 0, 0, 0);
            }
        } else {
            // gh gates (3..5) consume hv
            #pragma unroll
            for (int t = 0; t < 7; ++t) {
                bfrag bv[3];
                #pragma unroll
                for (int g = 0; g < 3; ++g)
                    bv[g] = *(const bfrag*)&Bcur[(size_t)(((g * 7 + t) * 64) + lane) * 8];
                #pragma unroll
                for (int g = 0; g < 3; ++g)
                    #pragma unroll
                    for (int mf = 0; mf < 2; ++mf)
                        acc[g + 3][mf] = __builtin_amdgcn_mfma_f32_16x16x32_bf16(hv[mf][t], bv[g], acc[g + 3][mf], 0, 0, 0);
            }

            // epilogue: C/D layout col=lane&15 (j), row=(lane>>4)*4+reg (m)
            float tmax = 0.0f;
            if (j < D) {
                float bir = g_bias[j],          biz = g_bias[DP + j],     bin = g_bias[2 * DP + j];
                float bhr = g_bias[3 * DP + j], bhz = g_bias[4 * DP + j], bhn = g_bias[5 * DP + j];
                #pragma unroll
                for (int mf = 0; mf < 2; ++mf) {
                    int m0 = wbase + mf * 16 + rowq;
                    #pragma unroll
                    for (int r = 0; r < 4; ++r) {
                        int m = m0 + r;
                        if (m < N_NODES) {
                            float hold = bf2f((short)hold_u[mf][r]);
                            float rr = fast_sigmoid(acc[0][mf][r] + bir + acc[3][mf][r] + bhr);
                            float zz = fast_sigmoid(acc[1][mf][r] + biz + acc[4][mf][r] + bhz);
                            float nn = fast_tanh(acc[2][mf][r] + bin + rr * (acc[5][mf][r] + bhn));
                            float hv2 = (1.0f - zz) * nn + zz * hold;
                            hnext[(size_t)m * KP + j] = __float2bfloat16(hv2);
                            if (hv2 > tmax) tmax = hv2;
                        }
                    }
                }
                if (dopool) atomicMax(&pmax[j], __float_as_uint(tmax));
            }
        }
    }

    if (dopool) {
        __syncthreads();
        for (int c = tid; c < D; c += 256) atomicMax(&pooled[c], pmax[c]);
    }
}

// ---------------- logits + softmax ----------------
__global__ void head_kernel(const unsigned int* __restrict__ pooled,
                            const float* __restrict__ cls_w,
                            const float* __restrict__ cls_b,
                            float* __restrict__ out) {
    if (threadIdx.x == 0) {
        float l0 = cls_b[0], l1 = cls_b[1];
        for (int d = 0; d < D; ++d) {
            float p = __uint_as_float(pooled[d]);
            l0 += p * cls_w[d];
            l1 += p * cls_w[D + d];
        }
        float mx = l0 > l1 ? l0 : l1;
        float e0 = expf(l0 - mx), e1 = expf(l1 - mx);
        out[0] = e0 / (e0 + e1);
        out[1] = e1 / (e0 + e1);
    }
}

extern "C" void kernel_launch(void* const* d_in, const int* in_sizes, int n_in,
                              void* d_out, int out_size, void* d_ws, size_t ws_size,
                              hipStream_t stream) {
    const float* x     = (const float*)d_in[0];
    const float* W     = (const float*)d_in[1];
    const float* w_ih  = (const float*)d_in[2];
    const float* w_hh  = (const float*)d_in[3];
    const float* b_ih  = (const float*)d_in[4];
    const float* b_hh  = (const float*)d_in[5];
    const float* cls_w = (const float*)d_in[6];
    const float* cls_b = (const float*)d_in[7];
    const int*   ei    = (const int*)d_in[8];
    const int* src = ei;
    const int* dst = ei + N_EDGES;

    const size_t ROWB = (size_t)N_PAD * KP;     // bf16 elements per buffer
    __hip_bfloat16* hA   = (__hip_bfloat16*)d_ws;
    __hip_bfloat16* hB   = hA + ROWB;
    int* cnt    = (int*)(hB + ROWB);
    int* incl   = cnt + N_NODES;
    int* bsum   = incl + N_NODES;
    int* off    = bsum + 128;
    int* cursor = off + N_NODES + 1;
    int* esrc   = cursor + N_NODES;
    unsigned int* pooled = (unsigned int*)(esrc + N_EDGES);

    // CSR build (once per call; edges are step-invariant)
    hipMemsetAsync(cnt, 0, N_NODES * sizeof(int), stream);
    count_kernel<<<(N_EDGES + 255) / 256, 256, 0, stream>>>(dst, cnt);
    scan1<<<(N_NODES + SCAN_B - 1) / SCAN_B, SCAN_B, 0, stream>>>(cnt, incl, bsum);
    scan2<<<1, 128, 0, stream>>>(bsum, (N_NODES + SCAN_B - 1) / SCAN_B);
    scan3<<<(N_NODES + 255) / 256, 256, 0, stream>>>(cnt, incl, bsum, off, cursor);
    fill_kernel<<<(N_EDGES + 255) / 256, 256, 0, stream>>>(src, dst, cursor, esrc);

    // weight prep
    wc_kernel<<<NUM_STEPS * 600, 256, 0, stream>>>(W, w_ih);
    wconv_kernel<<<(NUM_STEPS * 13 * 6 * 7 * 64) / 256, 256, 0, stream>>>(w_hh);
    bias_kernel<<<(6 * DP + 255) / 256, 256, 0, stream>>>(b_ih, b_hh);

    pad_kernel<<<(int)(ROWB / 256), 256, 0, stream>>>(x, hA);
    hipMemsetAsync(pooled, 0, D * sizeof(unsigned int), stream);

    __hip_bfloat16* hcur = hA;
    __hip_bfloat16* hnext = hB;
    for (int s = 0; s < NUM_STEPS; ++s) {
        gru_fused<<<N_PAD / 128, 256, 0, stream>>>(hcur, hnext, off, esrc, pooled, s);
        __hip_bfloat16* t = hcur; hcur = hnext; hnext = t;
    }
    head_kernel<<<1, 64, 0, stream>>>(pooled, cls_w, cls_b, (float*)d_out);
}

// Round 11
// 841.565 us; speedup vs baseline: 1.5897x; 1.0608x over previous
//
#include <hip/hip_runtime.h>
#include <hip/hip_bf16.h>
#include <math.h>

#define N_NODES 100000
#define N_PAD   100096   // multiple of 256
#define N_EDGES 400000
#define IN_DIM  100
#define D       200
#define DP      208      // j padded to 13*16
#define KP      224      // k padded to 7*32
#define NUM_STEPS 4

#define TILE_SHORTS  21504         // full jt tile: 6 gates * 7 kt * 64 lanes * 8 shorts
#define HALF_SHORTS  10752         // 3 gates
#define HALF_GROUPS  21            // 1344 chunks / 64 lanes
#define EIDX_CAP     896           // per-wave LDS edge-index capacity

typedef __attribute__((ext_vector_type(8))) short bfrag;   // 8 bf16 (4 VGPRs)
typedef __attribute__((ext_vector_type(4))) float facc;    // 4 fp32

// Wc[s] = w_ih @ W[s]^T so that gi = aggr_raw @ Wc[s]^T  (scatter is linear)
__device__ float g_Wc[NUM_STEPS * 600 * D];
// weights, per-(step,jt) CONTIGUOUS tile: [s][jt][g6][t7][lane64][8]
__device__ short g_Wall[NUM_STEPS * 13 * TILE_SHORTS];
__device__ float g_bias[6 * DP];

__device__ __forceinline__ float fast_sigmoid(float x) {
    return __builtin_amdgcn_rcpf(1.0f + __expf(-x));
}
__device__ __forceinline__ float fast_tanh(float x) {
    return 2.0f * __builtin_amdgcn_rcpf(1.0f + __expf(-2.0f * x)) - 1.0f;
}
__device__ __forceinline__ float bf2f(short u) {
    unsigned int x = ((unsigned int)(unsigned short)u) << 16;
    return __uint_as_float(x);
}

// ---------------- Wc precompute: block=(s*600+j), thread=k ----------------
__global__ __launch_bounds__(256) void wc_kernel(const float* __restrict__ W,
                                                 const float* __restrict__ w_ih) {
    int s = blockIdx.x / 600;
    int j = blockIdx.x % 600;
    int k = threadIdx.x;
    if (k >= D) return;
    const float* wr = &w_ih[(size_t)j * D];
    const float* Wr = &W[(size_t)s * D * D + (size_t)k * D];
    float acc = 0.0f;
    #pragma unroll 4
    for (int t = 0; t < D; ++t) acc += wr[t] * Wr[t];
    g_Wc[((size_t)s * 600 + j) * D + k] = acc;
}

// ---------------- permute weights into per-tile fragment order (bf16) ----------------
// output idx = (((s*13 + jt)*6 + g)*7 + t)*64 + l, 8 shorts each
__global__ __launch_bounds__(256) void wconv_kernel(const float* __restrict__ w_hh) {
    int idx = blockIdx.x * 256 + threadIdx.x;   // < 4*13*6*7*64 = 139776
    int l  = idx & 63;
    int t  = (idx >> 6) % 7;
    int g  = (idx / 448) % 6;
    int jt = (idx / 2688) % 13;
    int s  = idx / 34944;
    int j  = jt * 16 + (l & 15);
    int k0 = t * 32 + (l >> 4) * 8;
    short* out = g_Wall + (size_t)idx * 8;
    #pragma unroll
    for (int i = 0; i < 8; ++i) {
        int k = k0 + i;
        float v = 0.0f;
        if (j < D && k < D)
            v = (g < 3) ? g_Wc[((size_t)s * 600 + g * 200 + j) * D + k]
                        : w_hh[((size_t)(g - 3) * 200 + j) * D + k];
        __hip_bfloat16 b = __float2bfloat16(v);
        out[i] = *reinterpret_cast<short*>(&b);
    }
}

__global__ void bias_kernel(const float* __restrict__ b_ih, const float* __restrict__ b_hh) {
    int idx = blockIdx.x * 256 + threadIdx.x;
    if (idx >= 6 * DP) return;
    int g = idx / DP, j = idx % DP;
    float v = 0.0f;
    if (j < D) v = (g < 3) ? b_ih[g * 200 + j] : b_hh[(g - 3) * 200 + j];
    g_bias[idx] = v;
}

// ---------------- pad: h[:, :100] = bf16(x), rest 0 ----------------
__global__ void pad_kernel(const float* __restrict__ x, __hip_bfloat16* __restrict__ h) {
    int idx = blockIdx.x * 256 + threadIdx.x;   // N_PAD*KP exact multiple of 256
    int n = idx / KP, c = idx % KP;
    float v = (n < N_NODES && c < IN_DIM) ? x[n * IN_DIM + c] : 0.0f;
    h[idx] = __float2bfloat16(v);
}

// ---------------- CSR build ----------------
__global__ void count_kernel(const int* __restrict__ dst, int* __restrict__ cnt) {
    int e = blockIdx.x * blockDim.x + threadIdx.x;
    if (e < N_EDGES) atomicAdd(&cnt[dst[e]], 1);
}

#define SCAN_B 1024
// 2-barrier block scan: wave shuffle-scan + cross-wave LDS
__global__ __launch_bounds__(SCAN_B) void scan1(const int* __restrict__ cnt,
                                                int* __restrict__ incl, int* __restrict__ bsum) {
    __shared__ int ws[16];
    int i = blockIdx.x * SCAN_B + threadIdx.x;
    int lane = threadIdx.x & 63, wid = threadIdx.x >> 6;
    int v = (i < N_NODES) ? cnt[i] : 0;
    int s = v;
    #pragma unroll
    for (int o = 1; o < 64; o <<= 1) {
        int t = __shfl_up(s, o, 64);
        if (lane >= o) s += t;
    }
    if (lane == 63) ws[wid] = s;
    __syncthreads();
    if (wid == 0) {
        int t = (lane < 16) ? ws[lane] : 0;
        #pragma unroll
        for (int o = 1; o < 16; o <<= 1) {
            int u = __shfl_up(t, o, 64);
            if (lane >= o) t += u;
        }
        if (lane < 16) ws[lane] = t;
    }
    __syncthreads();
    if (wid > 0) s += ws[wid - 1];
    if (i < N_NODES) incl[i] = s;
    if (threadIdx.x == SCAN_B - 1) bsum[blockIdx.x] = s;
}
__global__ void scan2(int* __restrict__ bsum, int nb) {
    __shared__ int sh[128];
    int v = (threadIdx.x < nb) ? bsum[threadIdx.x] : 0;
    sh[threadIdx.x] = v; __syncthreads();
    for (int off = 1; off < 128; off <<= 1) {
        int t = (threadIdx.x >= off) ? sh[threadIdx.x - off] : 0;
        __syncthreads();
        sh[threadIdx.x] += t;
        __syncthreads();
    }
    if (threadIdx.x < nb) bsum[threadIdx.x] = sh[threadIdx.x] - v;  // exclusive
}
__global__ void scan3(const int* __restrict__ cnt, const int* __restrict__ incl,
                      const int* __restrict__ bsum, int* __restrict__ off,
                      int* __restrict__ cursor) {
    int i = blockIdx.x * blockDim.x + threadIdx.x;
    if (i < N_NODES) {
        int v = incl[i] - cnt[i] + bsum[i / SCAN_B];
        off[i] = v; cursor[i] = v;
    }
    if (i == 0) off[N_NODES] = N_EDGES;
}
__global__ void fill_kernel(const int* __restrict__ src, const int* __restrict__ dst,
                            int* __restrict__ cursor, int* __restrict__ esrc) {
    int e = blockIdx.x * blockDim.x + threadIdx.x;
    if (e < N_EDGES) {
        int pos = atomicAdd(&cursor[dst[e]], 1);
        esrc[pos] = src[e];
    }
}

// ---------------- async stage: one HALF tile (21504 B) global -> LDS ----------------
__device__ __forceinline__ void stage_half(const short* __restrict__ gsrc,
                                           short* lds_dst, int wave, int lane) {
    #pragma unroll
    for (int g = wave; g < HALF_GROUPS; g += 4) {
        __builtin_amdgcn_global_load_lds(
            (const __attribute__((address_space(1))) void*)(gsrc + g * 512 + lane * 8),
            (__attribute__((address_space(3))) void*)(lds_dst + g * 512),
            16, 0, 0);
    }
}

// ---------------- fused gather + MFMA GRU (+ pool on last step) ----------------
// grid N_PAD/128; block 256 = 4 waves; wave: 32 rows.
// Phase 1: prefetch wave's contiguous esrc slice into LDS, then gather 32 aggr
//          rows, 4 rows in flight x 4-edge unroll (8-32 16B loads outstanding),
//          via per-wave LDS scratch -> av register fragments.
// Phase 2: 26 half-tile iterations, double-buffered DMA (unchanged from r10).
__global__ __launch_bounds__(256, 2) void gru_fused(const __hip_bfloat16* __restrict__ hcur,
                                                    __hip_bfloat16* __restrict__ hnext,
                                                    const int* __restrict__ off,
                                                    const int* __restrict__ esrc,
                                                    unsigned int* __restrict__ pooled,
                                                    int step) {
    __shared__ short Bs[2][HALF_SHORTS];  // 43008 B; bytes 0..28671 = A-scratch,
                                          // bytes 28672..43007 = edge-index cache
    __shared__ unsigned int pmax[DP];     // step-3 pooling scratch
    int tid = threadIdx.x;
    int lane = tid & 63, wave = tid >> 6;
    int wbase = blockIdx.x * 128 + wave * 32;
    int mrow = lane & 15, kq = lane >> 4;
    bool dopool = (step == NUM_STEPS - 1);

    if (dopool) for (int c = tid; c < DP; c += 256) pmax[c] = 0u;

    short* LDSbase = &Bs[0][0];
    short* Awave = LDSbase + wave * 16 * KP;               // 16 rows x 224 shorts
    int* EIdx = (int*)((char*)LDSbase + 28672) + wave * EIDX_CAP;

    // ---- prefetch this wave's contiguous esrc slice (CSR rows are contiguous) ----
    int nlo = wbase < N_NODES ? wbase : N_NODES;
    int nhi = (wbase + 32) < N_NODES ? (wbase + 32) : N_NODES;
    int lo = off[nlo];
    int cntw = off[nhi] - lo;
    bool use_lds = (cntw <= EIDX_CAP);
    if (use_lds)
        for (int i = lane; i < cntw; i += 64) EIdx[i] = esrc[lo + i];

    bfrag av[2][7], hv[2][7];

    // ---- gather: 2 phases x 16 rows; 4 rows in flight, 4-edge unroll ----
    int r4 = lane >> 4;              // row-in-flight 0..3
    int ck = lane & 15;              // 16B chunk id (this lane also covers ck+16)
    int colA = ck * 8;
    int colB = colA + 128;           // (ck+16)*8
    bool sumB = (ck < 9);            // chunks 16..24 carry data (cols < 200)
    #pragma unroll
    for (int p = 0; p < 2; ++p) {
        #pragma unroll
        for (int it = 0; it < 4; ++it) {
            int rr = it * 4 + r4;            // row within phase
            int n = wbase + p * 16 + rr;
            float a[8] = {0, 0, 0, 0, 0, 0, 0, 0};
            float b[8] = {0, 0, 0, 0, 0, 0, 0, 0};
            if (n < N_NODES) {
                int e0 = off[n] - lo, e1 = off[n + 1] - lo;
                int e = e0;
                for (; e + 3 < e1; e += 4) {
                    int i0, i1, i2, i3;
                    if (use_lds) {
                        i0 = EIdx[e]; i1 = EIdx[e + 1]; i2 = EIdx[e + 2]; i3 = EIdx[e + 3];
                    } else {
                        i0 = esrc[lo + e];     i1 = esrc[lo + e + 1];
                        i2 = esrc[lo + e + 2]; i3 = esrc[lo + e + 3];
                    }
                    size_t s0 = (size_t)i0 * KP, s1 = (size_t)i1 * KP;
                    size_t s2 = (size_t)i2 * KP, s3 = (size_t)i3 * KP;
                    bfrag a0 = *(const bfrag*)(hcur + s0 + colA);
                    bfrag a1 = *(const bfrag*)(hcur + s1 + colA);
                    bfrag a2 = *(const bfrag*)(hcur + s2 + colA);
                    bfrag a3 = *(const bfrag*)(hcur + s3 + colA);
                    if (sumB) {
                        bfrag b0 = *(const bfrag*)(hcur + s0 + colB);
                        bfrag b1 = *(const bfrag*)(hcur + s1 + colB);
                        bfrag b2 = *(const bfrag*)(hcur + s2 + colB);
                        bfrag b3 = *(const bfrag*)(hcur + s3 + colB);
                        #pragma unroll
                        for (int q = 0; q < 8; ++q)
                            b[q] += (bf2f(b0[q]) + bf2f(b1[q])) + (bf2f(b2[q]) + bf2f(b3[q]));
                    }
                    #pragma unroll
                    for (int q = 0; q < 8; ++q)
                        a[q] += (bf2f(a0[q]) + bf2f(a1[q])) + (bf2f(a2[q]) + bf2f(a3[q]));
                }
                for (; e < e1; ++e) {
                    int i0 = use_lds ? EIdx[e] : esrc[lo + e];
                    size_t s0 = (size_t)i0 * KP;
                    bfrag a0 = *(const bfrag*)(hcur + s0 + colA);
                    if (sumB) {
                        bfrag b0 = *(const bfrag*)(hcur + s0 + colB);
                        #pragma unroll
                        for (int q = 0; q < 8; ++q) b[q] += bf2f(b0[q]);
                    }
                    #pragma unroll
                    for (int q = 0; q < 8; ++q) a[q] += bf2f(a0[q]);
                }
            }
            __hip_bfloat16 oa[8], ob[8];
            #pragma unroll
            for (int q = 0; q < 8; ++q) {
                oa[q] = __float2bfloat16(a[q]);
                ob[q] = __float2bfloat16(b[q]);
            }
            *(ushort4*)(Awave + rr * KP + colA)     = *(const ushort4*)&oa[0];
            *(ushort4*)(Awave + rr * KP + colA + 4) = *(const ushort4*)&oa[4];
            if (ck < 12) {   // chunks 16..27 (25..27 are zero pads; b stayed 0)
                *(ushort4*)(Awave + rr * KP + colB)     = *(const ushort4*)&ob[0];
                *(ushort4*)(Awave + rr * KP + colB + 4) = *(const ushort4*)&ob[4];
            }
        }
        // read this phase's A fragments (own-wave LDS region only)
        #pragma unroll
        for (int t = 0; t < 7; ++t)
            av[p][t] = *(const bfrag*)&Awave[mrow * KP + t * 32 + kq * 8];
    }

    // ---- load this wave's H fragments from global (contiguous rows) ----
    size_t hbase = (size_t)(wbase + mrow) * KP + kq * 8;
    #pragma unroll
    for (int mf = 0; mf < 2; ++mf)
        #pragma unroll
        for (int t = 0; t < 7; ++t)
            hv[mf][t] = *(const bfrag*)(hcur + hbase + mf * 16 * KP + t * 32);

    const short* Wstep = g_Wall + (size_t)step * 13 * TILE_SHORTS;
    int jcol = lane & 15;
    int rowq = (lane >> 4) * 4;

    __syncthreads();                       // A-scratch reads complete; LDS -> B buffers
    stage_half(Wstep, &Bs[0][0], wave, lane);   // h0 = (jt0, gi-gates)

    facc acc[6][2];
    unsigned short hold_u[2][4];

    for (int hk = 0; hk < 26; ++hk) {
        __syncthreads();   // h_hk DMA complete; buf[(hk+1)&1] free for restage
        if (hk + 1 < 26)
            stage_half(Wstep + (size_t)(hk + 1) * HALF_SHORTS,
                       &Bs[(hk + 1) & 1][0], wave, lane);

        int jt = hk >> 1;
        int j = jt * 16 + jcol;
        const short* Bcur = &Bs[hk & 1][0];

        if ((hk & 1) == 0) {
            // preload old-h for this jt's epilogue (latency hides under both halves)
            #pragma unroll
            for (int mf = 0; mf < 2; ++mf)
                #pragma unroll
                for (int r = 0; r < 4; ++r)
                    hold_u[mf][r] = *(const unsigned short*)
                        (hcur + (size_t)(wbase + mf * 16 + rowq + r) * KP + j);
            #pragma unroll
            for (int g = 0; g < 6; ++g)
                #pragma unroll
                for (int mf = 0; mf < 2; ++mf) acc[g][mf] = (facc)(0.0f);
            // gi gates (0..2) consume av
            #pragma unroll
            for (int t = 0; t < 7; ++t) {
                bfrag bv[3];
                #pragma unroll
                for (int g = 0; g < 3; ++g)
                    bv[g] = *(const bfrag*)&Bcur[(size_t)(((g * 7 + t) * 64) + lane) * 8];
                #pragma unroll
                for (int g = 0; g < 3; ++g)
                    #pragma unroll
                    for (int mf = 0; mf < 2; ++mf)
                        acc[g][mf] = __builtin_amdgcn_mfma_f32_16x16x32_bf16(av[mf][t], bv[g], acc[g][mf], 0, 0, 0);
            }
        } else {
            // gh gates (3..5) consume hv
            #pragma unroll
            for (int t = 0; t < 7; ++t) {
                bfrag bv[3];
                #pragma unroll
                for (int g = 0; g < 3; ++g)
                    bv[g] = *(const bfrag*)&Bcur[(size_t)(((g * 7 + t) * 64) + lane) * 8];
                #pragma unroll
                for (int g = 0; g < 3; ++g)
                    #pragma unroll
                    for (int mf = 0; mf < 2; ++mf)
                        acc[g + 3][mf] = __builtin_amdgcn_mfma_f32_16x16x32_bf16(hv[mf][t], bv[g], acc[g + 3][mf], 0, 0, 0);
            }

            // epilogue: C/D layout col=lane&15 (j), row=(lane>>4)*4+reg (m)
            float tmax = 0.0f;
            if (j < D) {
                float bir = g_bias[j],          biz = g_bias[DP + j],     bin = g_bias[2 * DP + j];
                float bhr = g_bias[3 * DP + j], bhz = g_bias[4 * DP + j], bhn = g_bias[5 * DP + j];
                #pragma unroll
                for (int mf = 0; mf < 2; ++mf) {
                    int m0 = wbase + mf * 16 + rowq;
                    #pragma unroll
                    for (int r = 0; r < 4; ++r) {
                        int m = m0 + r;
                        if (m < N_NODES) {
                            float hold = bf2f((short)hold_u[mf][r]);
                            float rr = fast_sigmoid(acc[0][mf][r] + bir + acc[3][mf][r] + bhr);
                            float zz = fast_sigmoid(acc[1][mf][r] + biz + acc[4][mf][r] + bhz);
                            float nn = fast_tanh(acc[2][mf][r] + bin + rr * (acc[5][mf][r] + bhn));
                            float hv2 = (1.0f - zz) * nn + zz * hold;
                            hnext[(size_t)m * KP + j] = __float2bfloat16(hv2);
                            if (hv2 > tmax) tmax = hv2;
                        }
                    }
                }
                if (dopool) atomicMax(&pmax[j], __float_as_uint(tmax));
            }
        }
    }

    if (dopool) {
        __syncthreads();
        for (int c = tid; c < D; c += 256) atomicMax(&pooled[c], pmax[c]);
    }
}

// ---------------- logits + softmax ----------------
__global__ void head_kernel(const unsigned int* __restrict__ pooled,
                            const float* __restrict__ cls_w,
                            const float* __restrict__ cls_b,
                            float* __restrict__ out) {
    if (threadIdx.x == 0) {
        float l0 = cls_b[0], l1 = cls_b[1];
        for (int d = 0; d < D; ++d) {
            float p = __uint_as_float(pooled[d]);
            l0 += p * cls_w[d];
            l1 += p * cls_w[D + d];
        }
        float mx = l0 > l1 ? l0 : l1;
        float e0 = expf(l0 - mx), e1 = expf(l1 - mx);
        out[0] = e0 / (e0 + e1);
        out[1] = e1 / (e0 + e1);
    }
}

extern "C" void kernel_launch(void* const* d_in, const int* in_sizes, int n_in,
                              void* d_out, int out_size, void* d_ws, size_t ws_size,
                              hipStream_t stream) {
    const float* x     = (const float*)d_in[0];
    const float* W     = (const float*)d_in[1];
    const float* w_ih  = (const float*)d_in[2];
    const float* w_hh  = (const float*)d_in[3];
    const float* b_ih  = (const float*)d_in[4];
    const float* b_hh  = (const float*)d_in[5];
    const float* cls_w = (const float*)d_in[6];
    const float* cls_b = (const float*)d_in[7];
    const int*   ei    = (const int*)d_in[8];
    const int* src = ei;
    const int* dst = ei + N_EDGES;

    const size_t ROWB = (size_t)N_PAD * KP;     // bf16 elements per buffer
    __hip_bfloat16* hA   = (__hip_bfloat16*)d_ws;
    __hip_bfloat16* hB   = hA + ROWB;
    int* cnt    = (int*)(hB + ROWB);
    int* incl   = cnt + N_NODES;
    int* bsum   = incl + N_NODES;
    int* off    = bsum + 128;
    int* cursor = off + N_NODES + 1;
    int* esrc   = cursor + N_NODES;
    unsigned int* pooled = (unsigned int*)(esrc + N_EDGES);

    // CSR build (once per call; edges are step-invariant)
    hipMemsetAsync(cnt, 0, N_NODES * sizeof(int), stream);
    count_kernel<<<(N_EDGES + 255) / 256, 256, 0, stream>>>(dst, cnt);
    scan1<<<(N_NODES + SCAN_B - 1) / SCAN_B, SCAN_B, 0, stream>>>(cnt, incl, bsum);
    scan2<<<1, 128, 0, stream>>>(bsum, (N_NODES + SCAN_B - 1) / SCAN_B);
    scan3<<<(N_NODES + 255) / 256, 256, 0, stream>>>(cnt, incl, bsum, off, cursor);
    fill_kernel<<<(N_EDGES + 255) / 256, 256, 0, stream>>>(src, dst, cursor, esrc);

    // weight prep
    wc_kernel<<<NUM_STEPS * 600, 256, 0, stream>>>(W, w_ih);
    wconv_kernel<<<(NUM_STEPS * 13 * 6 * 7 * 64) / 256, 256, 0, stream>>>(w_hh);
    bias_kernel<<<(6 * DP + 255) / 256, 256, 0, stream>>>(b_ih, b_hh);

    pad_kernel<<<(int)(ROWB / 256), 256, 0, stream>>>(x, hA);
    hipMemsetAsync(pooled, 0, D * sizeof(unsigned int), stream);

    __hip_bfloat16* hcur = hA;
    __hip_bfloat16* hnext = hB;
    for (int s = 0; s < NUM_STEPS; ++s) {
        gru_fused<<<N_PAD / 128, 256, 0, stream>>>(hcur, hnext, off, esrc, pooled, s);
        __hip_bfloat16* t = hcur; hcur = hnext; hnext = t;
    }
    head_kernel<<<1, 64, 0, stream>>>(pooled, cls_w, cls_b, (float*)d_out);
}